// Round 15
// baseline (257.734 us; speedup 1.0000x reference)
//
#include <hip/hip_runtime.h>

#define B_      8
#define N_      1024
#define DIN_    64
#define H_      128
#define MSG2    128
#define L_      5
#define TGT_    12
#define NLAYERS_ 3
#define CAT_    640          // L_ * MSG2
#define NODES   (B_ * N_)    // 8192
#define KSPLIT  3

typedef __attribute__((ext_vector_type(8))) short s16x8;
typedef __attribute__((ext_vector_type(4))) float f32x4;

#define GLD16(G, L) __builtin_amdgcn_global_load_lds( \
    (const __attribute__((address_space(1))) void*)(G), \
    (__attribute__((address_space(3))) void*)(L), 16, 0, 0)

__device__ __forceinline__ float sigmoidf_(float x) { return 1.f / (1.f + __expf(-x)); }

__device__ __forceinline__ unsigned short f2bf(float x) {
  unsigned int u = __float_as_uint(x);
  u += 0x7FFFu + ((u >> 16) & 1u);      // round-to-nearest-even
  return (unsigned short)(u >> 16);
}
__device__ __forceinline__ float bf2f(unsigned short u) {
  return __uint_as_float(((unsigned int)u) << 16);
}

// ---------------- init: pad h_in -> h0/h (fp32), X=h hi/lo bf16, masks ----------------
__global__ __launch_bounds__(256) void k_init(const float* __restrict__ h_in,
                                              float* __restrict__ h,
                                              float* __restrict__ h0,
                                              unsigned short* __restrict__ X,
                                              float* __restrict__ maskA,
                                              float* __restrict__ maskR) {
  int node = blockIdx.x * 4 + (threadIdx.x >> 6);
  int lane = threadIdx.x & 63;
  float v = h_in[(size_t)node * DIN_ + lane];
  size_t base = (size_t)node * H_;
  h[base + lane] = v;   h[base + 64 + lane] = 0.f;
  h0[base + lane] = v;  h0[base + 64 + lane] = 0.f;
  unsigned short hi = f2bf(v);
  unsigned short lo = f2bf(v - bf2f(hi));
  size_t xb = (size_t)node * 256;
  X[xb + lane] = hi;        X[xb + 64 + lane] = 0;
  X[xb + 128 + lane] = lo;  X[xb + 192 + lane] = 0;
  float sa = fabsf(v), ss = v;
  for (int off = 32; off > 0; off >>= 1) {
    sa += __shfl_down(sa, off);
    ss += __shfl_down(ss, off);
  }
  if (lane == 0) {
    maskA[node] = (sa > 0.f) ? 1.f : 0.f;
    maskR[node] = (ss > 0.f) ? 1.f : 0.f;
  }
}

// ---------------- pack: Gb = bf16(g), Eb = u8(e)  (once) ----------------
__global__ __launch_bounds__(256) void k_pack(const float* __restrict__ g,
                                              const int* __restrict__ e,
                                              unsigned short* __restrict__ Gb,
                                              unsigned char* __restrict__ Eb) {
  size_t i8 = ((size_t)blockIdx.x * 256 + threadIdx.x) * 8;
  float4 g0 = *(const float4*)&g[i8];
  float4 g1 = *(const float4*)&g[i8 + 4];
  int4   e0 = *(const int4*)&e[i8];
  int4   e1 = *(const int4*)&e[i8 + 4];
  ushort4 ga, gb;
  ga.x = f2bf(g0.x); ga.y = f2bf(g0.y); ga.z = f2bf(g0.z); ga.w = f2bf(g0.w);
  gb.x = f2bf(g1.x); gb.y = f2bf(g1.y); gb.z = f2bf(g1.z); gb.w = f2bf(g1.w);
  *(ushort4*)&Gb[i8]     = ga;
  *(ushort4*)&Gb[i8 + 4] = gb;
  uint2 ev;
  ev.x = (unsigned)(e0.x & 0xFF) | ((unsigned)(e0.y & 0xFF) << 8) |
         ((unsigned)(e0.z & 0xFF) << 16) | ((unsigned)(e0.w & 0xFF) << 24);
  ev.y = (unsigned)(e1.x & 0xFF) | ((unsigned)(e1.y & 0xFF) << 8) |
         ((unsigned)(e1.z & 0xFF) << 16) | ((unsigned)(e1.w & 0xFF) << 24);
  *(uint2*)&Eb[i8] = ev;
}

// ---------------- aprep: ATh/ATl[c][d] = bf16 hi/lo of A[l][d][o], c=l*128+o ----------------
__global__ __launch_bounds__(256) void k_aprep(const float* __restrict__ A,
                                               unsigned short* __restrict__ ATh,
                                               unsigned short* __restrict__ ATl) {
  int idx = blockIdx.x * 256 + threadIdx.x;
  if (idx >= CAT_ * 128) return;
  int c = idx >> 7, d = idx & 127;
  int l = c >> 7, o = c & 127;
  float v = A[((size_t)l * 128 + d) * 128 + o];
  unsigned short hi = f2bf(v);
  ATh[idx] = hi;
  ATl[idx] = f2bf(v - bf2f(hi));
}

// ---------------- wprep: W{i,h}T hi/lo [c][k] bf16 (transposed) ----------------
__global__ __launch_bounds__(256) void k_wprep(const float* __restrict__ Wi,
                                               const float* __restrict__ Wh,
                                               unsigned short* __restrict__ WiTh,
                                               unsigned short* __restrict__ WiTl,
                                               unsigned short* __restrict__ WhTh,
                                               unsigned short* __restrict__ WhTl) {
  int idx = blockIdx.x * 256 + threadIdx.x;
  if (idx < 384 * 128) {
    int c = idx >> 7, k = idx & 127;
    float v = Wi[(size_t)k * 384 + c];
    unsigned short hi = f2bf(v);
    WiTh[idx] = hi; WiTl[idx] = f2bf(v - bf2f(hi));
  } else if (idx < 2 * 384 * 128) {
    int i = idx - 384 * 128;
    int c = i >> 7, k = i & 127;
    float v = Wh[(size_t)k * 384 + c];
    unsigned short hi = f2bf(v);
    WhTh[i] = hi; WhTl[i] = f2bf(v - bf2f(hi));
  }
}

// ---------------- McatT[b][l][o][w] via split-precision bf16 MFMA ----------------
__global__ __launch_bounds__(256) void k_gemmT(const unsigned short* __restrict__ X,
                                               const unsigned short* __restrict__ ATh,
                                               const unsigned short* __restrict__ ATl,
                                               unsigned short* __restrict__ McatT) {
  __shared__ __align__(16) unsigned short Ah[64 * 40];
  __shared__ __align__(16) unsigned short Al[64 * 40];
  __shared__ __align__(16) unsigned short Bh[128 * 40];
  __shared__ __align__(16) unsigned short Bl2[128 * 40];
  const int tid = threadIdx.x;
  const int c0 = blockIdx.x * 128;
  const int node0 = blockIdx.y * 64;
  const int b = node0 >> 10;
  const int w0 = node0 & 1023;
  const int wid = tid >> 6, lane = tid & 63;
  const int wr = wid >> 1, wc = wid & 1;
  const int lr = lane & 15, lg = lane >> 4;
  const int ar = tid >> 2, aq = (tid & 3) * 8;
  const int br = tid >> 1, bq = (tid & 1) * 16;
  f32x4 acc[2][4];
  #pragma unroll
  for (int m = 0; m < 2; ++m)
    #pragma unroll
    for (int n = 0; n < 4; ++n) acc[m][n] = {0.f, 0.f, 0.f, 0.f};
  for (int kk = 0; kk < 4; ++kk) {
    const int kb = kk * 32;
    *(uint4*)&Ah[ar * 40 + aq] = *(const uint4*)&X[(size_t)(node0 + ar) * 256 + kb + aq];
    *(uint4*)&Al[ar * 40 + aq] = *(const uint4*)&X[(size_t)(node0 + ar) * 256 + 128 + kb + aq];
    const unsigned short* bh = ATh + (size_t)(c0 + br) * 128 + kb + bq;
    const unsigned short* bl = ATl + (size_t)(c0 + br) * 128 + kb + bq;
    *(uint4*)&Bh[br * 40 + bq]      = *(const uint4*)bh;
    *(uint4*)&Bh[br * 40 + bq + 8]  = *(const uint4*)(bh + 8);
    *(uint4*)&Bl2[br * 40 + bq]     = *(const uint4*)bl;
    *(uint4*)&Bl2[br * 40 + bq + 8] = *(const uint4*)(bl + 8);
    __syncthreads();
    s16x8 ah[2], al[2], bhf[4], blf[4];
    #pragma unroll
    for (int m = 0; m < 2; ++m) {
      int row = (wr * 32 + m * 16 + lr) * 40 + lg * 8;
      ah[m] = *(const s16x8*)&Ah[row];
      al[m] = *(const s16x8*)&Al[row];
    }
    #pragma unroll
    for (int n = 0; n < 4; ++n) {
      int row = (wc * 64 + n * 16 + lr) * 40 + lg * 8;
      bhf[n] = *(const s16x8*)&Bh[row];
      blf[n] = *(const s16x8*)&Bl2[row];
    }
    #pragma unroll
    for (int m = 0; m < 2; ++m)
      #pragma unroll
      for (int n = 0; n < 4; ++n) {
        acc[m][n] = __builtin_amdgcn_mfma_f32_16x16x32_bf16(ah[m], bhf[n], acc[m][n], 0, 0, 0);
        acc[m][n] = __builtin_amdgcn_mfma_f32_16x16x32_bf16(ah[m], blf[n], acc[m][n], 0, 0, 0);
        acc[m][n] = __builtin_amdgcn_mfma_f32_16x16x32_bf16(al[m], bhf[n], acc[m][n], 0, 0, 0);
      }
    __syncthreads();
  }
  #pragma unroll
  for (int m = 0; m < 2; ++m)
    #pragma unroll
    for (int n = 0; n < 4; ++n) {
      int c = c0 + wc * 64 + n * 16 + lr;
      int l = c >> 7, o = c & 127;
      int w = w0 + wr * 32 + m * 16 + lg * 4;
      ushort4 v;
      v.x = f2bf(acc[m][n][0]); v.y = f2bf(acc[m][n][1]);
      v.z = f2bf(acc[m][n][2]); v.w = f2bf(acc[m][n][3]);
      *(ushort4*)&McatT[(((size_t)b * L_ + l) * MSG2 + o) * N_ + w] = v;
    }
}

// ---------------- agg via 5 masked bf16 MFMA GEMMs ----------------
// 64v x 64o tile, KSPLIT=3 (grid 768 = 3 blocks/CU balanced), XOR-swizzled LDS.
// global_load_lds 2-phase double-buffer: loads never touch VGPRs (r7/r10 spill
// impossible); one __syncthreads per iter drains vmcnt (T3 minimum template).
// Linear LDS dest + inverse-swizzled SOURCE + swizzled read (m231 rule):
//   stored(rs,cs) = G[rs ^ ((rs>>2)&1)][cs ^ ((row&3)<<4)]
__global__ __launch_bounds__(256, 3) void k_agg_mfma(const unsigned short* __restrict__ Gb,
                                                     const unsigned char* __restrict__ Eb,
                                                     const unsigned short* __restrict__ McatT,
                                                     float* __restrict__ aggP) {
  __shared__ __align__(16) unsigned short GtS[2][64 * 32];      // 2 x 4 KB
  __shared__ __align__(16) unsigned char  EtS[2][64 * 40];      // 2 x 2.5 KB
  __shared__ __align__(16) unsigned short BlS[2][L_][64 * 32];  // 2 x 20 KB
  char* GtB = (char*)GtS;   // buffer stride 4096 B
  char* EtB = (char*)EtS;   // buffer stride 2560 B
  char* BlB = (char*)BlS;   // buffer stride 20480 B, label stride 4096 B

  const int tid = threadIdx.x;
  // XCD grouping: 32 blocks sharing (ks,b) -> same XCD (Mcat L2 reuse).
  const int fid = blockIdx.x;          // 0..767
  const int xcd = fid & 7;
  const int s   = fid >> 3;            // 0..95
  const int p   = xcd * 3 + (s >> 5);  // (ks,b) pair 0..23
  const int idx = s & 31;
  const int v0  = (idx & 15) * 64;
  const int oh  = idx >> 4;            // o-half 0/1
  const int ks  = p >> 3;              // 0..2
  const int b   = p & 7;

  const int wid  = tid >> 6, lane = tid & 63;
  const int wr   = wid >> 1, wc = wid & 1;    // wave tile 32v x 32o
  const int lr   = lane & 15, lg = lane >> 4;

  f32x4 acc[2][2];
  #pragma unroll
  for (int m = 0; m < 2; ++m)
    #pragma unroll
    for (int n = 0; n < 2; ++n) acc[m][n] = {0.f, 0.f, 0.f, 0.f};

  const int ar = tid >> 2, aq = (tid & 3) * 8;
  // inverse-swizzle source mapping for linear dest slot (ar, aq):
  const int rsrc = ar ^ ((ar >> 2) & 1);
  const int kq   = aq ^ ((rsrc & 3) << 3);     // shorts
  const size_t garow  = ((size_t)b * N_ + v0 + ar) * N_;        // Et (unswizzled)
  const size_t garowS = ((size_t)b * N_ + v0 + rsrc) * N_;      // gload source
  const size_t mrowS  = (((size_t)b * L_) * MSG2 + oh * 64 + rsrc) * N_;
  const size_t lstep  = (size_t)MSG2 * N_;
  const int ksbase = ks * 352;                 // 0, 352, 704
  const int ntile  = (ks == 2) ? 10 : 11;      // 11+11+10 = 32 tiles of k=32

  const int ldst = tid * 16;                   // linear LDS dest (bytes)
  const int et_w = ar * 40 + aq;
  const int fsw  = (lr & 7) << 4;

  // prologue: stage tile 0 -> buffer 0
  {
    const int kb = ksbase;
    GLD16(Gb + garowS + kb + kq, GtB + ldst);
    #pragma unroll
    for (int l = 0; l < L_; ++l)
      GLD16(McatT + mrowS + (size_t)l * lstep + kb + kq, BlB + l * 4096 + ldst);
    uint2 ev0 = *(const uint2*)&Eb[garow + kb + aq];
    *(uint2*)(EtB + et_w) = ev0;
  }
  __syncthreads();

  for (int kk = 0; kk < ntile; ++kk) {
    const int cur = kk & 1;
    const int nxt = cur ^ 1;
    uint2 ev;
    if (kk + 1 < ntile) {                      // issue next tile (stays in flight)
      const int kb = ksbase + (kk + 1) * 32;
      GLD16(Gb + garowS + kb + kq, GtB + nxt * 4096 + ldst);
      #pragma unroll
      for (int l = 0; l < L_; ++l)
        GLD16(McatT + mrowS + (size_t)l * lstep + kb + kq,
              BlB + nxt * 20480 + l * 4096 + ldst);
      ev = *(const uint2*)&Eb[garow + kb + aq];
    }

    // compute from buffer cur (gload_lds latency hides under this)
    {
      const char* Gc = GtB + cur * 4096;
      const char* Ec = EtB + cur * 2560;
      const char* Bc = BlB + cur * 20480;
      s16x8 gt[2]; uint2 et[2];
      #pragma unroll
      for (int m = 0; m < 2; ++m) {
        int row = wr * 32 + m * 16 + lr;
        gt[m] = *(const s16x8*)(Gc + ((row * 64 + lg * 16) ^ fsw));
        et[m] = *(const uint2*)(Ec + row * 40 + lg * 8);
      }
      #pragma unroll
      for (int l = 0; l < L_; ++l) {
        s16x8 bfr[2];
        #pragma unroll
        for (int n = 0; n < 2; ++n) {
          int row = wc * 32 + n * 16 + lr;
          bfr[n] = *(const s16x8*)(Bc + l * 4096 + ((row * 64 + lg * 16) ^ fsw));
        }
        #pragma unroll
        for (int m = 0; m < 2; ++m) {
          unsigned int w0e = et[m].x, w1e = et[m].y;
          s16x8 af;
          af[0] = (((w0e      ) & 0xFFu) == (unsigned)l) ? gt[m][0] : (short)0;
          af[1] = (((w0e >>  8) & 0xFFu) == (unsigned)l) ? gt[m][1] : (short)0;
          af[2] = (((w0e >> 16) & 0xFFu) == (unsigned)l) ? gt[m][2] : (short)0;
          af[3] = (((w0e >> 24) & 0xFFu) == (unsigned)l) ? gt[m][3] : (short)0;
          af[4] = (((w1e      ) & 0xFFu) == (unsigned)l) ? gt[m][4] : (short)0;
          af[5] = (((w1e >>  8) & 0xFFu) == (unsigned)l) ? gt[m][5] : (short)0;
          af[6] = (((w1e >> 16) & 0xFFu) == (unsigned)l) ? gt[m][6] : (short)0;
          af[7] = (((w1e >> 24) & 0xFFu) == (unsigned)l) ? gt[m][7] : (short)0;
          #pragma unroll
          for (int n = 0; n < 2; ++n)
            acc[m][n] = __builtin_amdgcn_mfma_f32_16x16x32_bf16(af, bfr[n], acc[m][n], 0, 0, 0);
        }
      }
    }

    if (kk + 1 < ntile) *(uint2*)(EtB + nxt * 2560 + et_w) = ev;  // regs die here
    __syncthreads();    // drains vmcnt(0): buffer nxt fully landed
  }

  float* op = aggP + ((size_t)ks * NODES + (size_t)b * N_ + v0) * MSG2 + oh * 64;
  #pragma unroll
  for (int m = 0; m < 2; ++m)
    #pragma unroll
    for (int n = 0; n < 2; ++n)
      #pragma unroll
      for (int j = 0; j < 4; ++j) {
        int row = wr * 32 + m * 16 + lg * 4 + j;
        int col = wc * 32 + n * 16 + lr;
        op[(size_t)row * MSG2 + col] = acc[m][n][j];
      }
}

// ---------------- xprep: Xm = hi/lo bf16 of summed agg slabs (KSPLIT=3) ----------------
__global__ __launch_bounds__(256) void k_xprep(const float* __restrict__ aggP,
                                               unsigned short* __restrict__ Xm) {
  const size_t slab = (size_t)NODES * MSG2;
  size_t i4 = ((size_t)blockIdx.x * 256 + threadIdx.x) * 4;
  float4 s;
  s.x = 0.f; s.y = 0.f; s.z = 0.f; s.w = 0.f;
  #pragma unroll
  for (int k = 0; k < KSPLIT; ++k) {
    float4 v = *(const float4*)&aggP[k * slab + i4];
    s.x += v.x; s.y += v.y; s.z += v.z; s.w += v.w;
  }
  size_t node = i4 >> 7;
  size_t j = i4 & 127;
  ushort4 hi, lo;
  hi.x = f2bf(s.x); lo.x = f2bf(s.x - bf2f(hi.x));
  hi.y = f2bf(s.y); lo.y = f2bf(s.y - bf2f(hi.y));
  hi.z = f2bf(s.z); lo.z = f2bf(s.z - bf2f(hi.z));
  hi.w = f2bf(s.w); lo.w = f2bf(s.w - bf2f(hi.w));
  *(ushort4*)&Xm[node * 256 + j]       = hi;
  *(ushort4*)&Xm[node * 256 + 128 + j] = lo;
}

// ---------------- gates via split-precision bf16 MFMA ----------------
__global__ __launch_bounds__(256) void k_gates_mfma(const unsigned short* __restrict__ Xm,
                                                    const unsigned short* __restrict__ Xh,
                                                    const unsigned short* __restrict__ WiTh,
                                                    const unsigned short* __restrict__ WiTl,
                                                    const unsigned short* __restrict__ WhTh,
                                                    const unsigned short* __restrict__ WhTl,
                                                    float* __restrict__ gates) {
  __shared__ __align__(16) unsigned short Ah[64 * 40];
  __shared__ __align__(16) unsigned short Al[64 * 40];
  __shared__ __align__(16) unsigned short Bh[128 * 40];
  __shared__ __align__(16) unsigned short Bl2[128 * 40];
  const int tid = threadIdx.x;
  const int z = blockIdx.z;
  const unsigned short* Xp  = z ? Xh : Xm;
  const unsigned short* WTh = z ? WhTh : WiTh;
  const unsigned short* WTl = z ? WhTl : WiTl;
  const int c0 = blockIdx.x * 128;
  const int node0 = blockIdx.y * 64;
  const int wid = tid >> 6, lane = tid & 63;
  const int wr = wid >> 1, wc = wid & 1;
  const int lr = lane & 15, lg = lane >> 4;
  const int ar = tid >> 2, aq = (tid & 3) * 8;
  const int br = tid >> 1, bq = (tid & 1) * 16;
  f32x4 acc[2][4];
  #pragma unroll
  for (int m = 0; m < 2; ++m)
    #pragma unroll
    for (int n = 0; n < 4; ++n) acc[m][n] = {0.f, 0.f, 0.f, 0.f};
  for (int kk = 0; kk < 4; ++kk) {
    const int kb = kk * 32;
    *(uint4*)&Ah[ar * 40 + aq] = *(const uint4*)&Xp[(size_t)(node0 + ar) * 256 + kb + aq];
    *(uint4*)&Al[ar * 40 + aq] = *(const uint4*)&Xp[(size_t)(node0 + ar) * 256 + 128 + kb + aq];
    const unsigned short* bh = WTh + (size_t)(c0 + br) * 128 + kb + bq;
    const unsigned short* bl = WTl + (size_t)(c0 + br) * 128 + kb + bq;
    *(uint4*)&Bh[br * 40 + bq]      = *(const uint4*)bh;
    *(uint4*)&Bh[br * 40 + bq + 8]  = *(const uint4*)(bh + 8);
    *(uint4*)&Bl2[br * 40 + bq]     = *(const uint4*)bl;
    *(uint4*)&Bl2[br * 40 + bq + 8] = *(const uint4*)(bl + 8);
    __syncthreads();
    s16x8 ah[2], al[2], bhf[4], blf[4];
    #pragma unroll
    for (int m = 0; m < 2; ++m) {
      int row = (wr * 32 + m * 16 + lr) * 40 + lg * 8;
      ah[m] = *(const s16x8*)&Ah[row];
      al[m] = *(const s16x8*)&Al[row];
    }
    #pragma unroll
    for (int n = 0; n < 4; ++n) {
      int row = (wc * 64 + n * 16 + lr) * 40 + lg * 8;
      bhf[n] = *(const s16x8*)&Bh[row];
      blf[n] = *(const s16x8*)&Bl2[row];
    }
    #pragma unroll
    for (int m = 0; m < 2; ++m)
      #pragma unroll
      for (int n = 0; n < 4; ++n) {
        acc[m][n] = __builtin_amdgcn_mfma_f32_16x16x32_bf16(ah[m], bhf[n], acc[m][n], 0, 0, 0);
        acc[m][n] = __builtin_amdgcn_mfma_f32_16x16x32_bf16(ah[m], blf[n], acc[m][n], 0, 0, 0);
        acc[m][n] = __builtin_amdgcn_mfma_f32_16x16x32_bf16(al[m], bhf[n], acc[m][n], 0, 0, 0);
      }
    __syncthreads();
  }
  #pragma unroll
  for (int m = 0; m < 2; ++m)
    #pragma unroll
    for (int n = 0; n < 4; ++n) {
      int c = c0 + wc * 64 + n * 16 + lr;
      int row = node0 + wr * 32 + m * 16 + lg * 4;
      #pragma unroll
      for (int j = 0; j < 4; ++j)
        gates[(size_t)(row + j) * 768 + z * 384 + c] = acc[m][n][j];
    }
}

// ---------------- GRU elementwise (+ X hi/lo write) ----------------
__global__ __launch_bounds__(256) void k_gru_elt(const float* __restrict__ gates,
                                                 const float* __restrict__ bi,
                                                 const float* __restrict__ bh,
                                                 const float* __restrict__ maskA,
                                                 float* __restrict__ h,
                                                 unsigned short* __restrict__ X) {
  const int t = threadIdx.x;
  const int node = blockIdx.x * 8 + (t >> 5);
  const int j4 = (t & 31) * 4;
  const size_t gb = (size_t)node * 768;
  float4 gir = *(const float4*)&gates[gb + j4];
  float4 giz = *(const float4*)&gates[gb + 128 + j4];
  float4 gin = *(const float4*)&gates[gb + 256 + j4];
  float4 ghr = *(const float4*)&gates[gb + 384 + j4];
  float4 ghz = *(const float4*)&gates[gb + 512 + j4];
  float4 ghn = *(const float4*)&gates[gb + 640 + j4];
  float4 bir = *(const float4*)&bi[j4];
  float4 biz = *(const float4*)&bi[128 + j4];
  float4 bin = *(const float4*)&bi[256 + j4];
  float4 bhr = *(const float4*)&bh[j4];
  float4 bhz = *(const float4*)&bh[128 + j4];
  float4 bhn = *(const float4*)&bh[256 + j4];
  float4 hv = *(const float4*)&h[(size_t)node * 128 + j4];
  float m = maskA[node];
  float4 ho;
  {
    float r = sigmoidf_(gir.x + bir.x + ghr.x + bhr.x);
    float z = sigmoidf_(giz.x + biz.x + ghz.x + bhz.x);
    float nn = tanhf(gin.x + bin.x + r * (ghn.x + bhn.x));
    ho.x = ((1.f - z) * nn + z * hv.x) * m;
  }
  {
    float r = sigmoidf_(gir.y + bir.y + ghr.y + bhr.y);
    float z = sigmoidf_(giz.y + biz.y + ghz.y + bhz.y);
    float nn = tanhf(gin.y + bin.y + r * (ghn.y + bhn.y));
    ho.y = ((1.f - z) * nn + z * hv.y) * m;
  }
  {
    float r = sigmoidf_(gir.z + bir.z + ghr.z + bhr.z);
    float z = sigmoidf_(giz.z + biz.z + ghz.z + bhz.z);
    float nn = tanhf(gin.z + bin.z + r * (ghn.z + bhn.z));
    ho.z = ((1.f - z) * nn + z * hv.z) * m;
  }
  {
    float r = sigmoidf_(gir.w + bir.w + ghr.w + bhr.w);
    float z = sigmoidf_(giz.w + biz.w + ghz.w + bhz.w);
    float nn = tanhf(gin.w + bin.w + r * (ghn.w + bhn.w));
    ho.w = ((1.f - z) * nn + z * hv.w) * m;
  }
  *(float4*)&h[(size_t)node * 128 + j4] = ho;
  ushort4 hi, lo;
  hi.x = f2bf(ho.x); lo.x = f2bf(ho.x - bf2f(hi.x));
  hi.y = f2bf(ho.y); lo.y = f2bf(ho.y - bf2f(hi.y));
  hi.z = f2bf(ho.z); lo.z = f2bf(ho.z - bf2f(hi.z));
  hi.w = f2bf(ho.w); lo.w = f2bf(ho.w - bf2f(hi.w));
  *(ushort4*)&X[(size_t)node * 256 + j4]       = hi;
  *(ushort4*)&X[(size_t)node * 256 + 128 + j4] = lo;
}

// ---------------- readout stage 1: PT[c][node] = ([hT,h0] @ Wcat)[node][c] ----------------
__global__ __launch_bounds__(256) void k_readP(const float* __restrict__ h,
                                               const float* __restrict__ h0,
                                               const float* __restrict__ Wg,
                                               const float* __restrict__ Wo,
                                               float* __restrict__ PT) {
  __shared__ float Xt[64][65];
  __shared__ float Wt[64][25];
  const int tid = threadIdx.x;
  const int node0 = blockIdx.x * 64;
  const int row = tid >> 2;
  const int cg  = tid & 3;
  float acc[6] = {0.f, 0.f, 0.f, 0.f, 0.f, 0.f};
  const int sr = tid >> 2;
  const int sk = (tid & 3) * 16;
  #pragma unroll
  for (int kb = 0; kb < 4; ++kb) {
    const float* src = (kb < 2 ? h : h0) + (size_t)(node0 + sr) * 128 + (kb & 1) * 64 + sk;
    #pragma unroll
    for (int q = 0; q < 4; ++q)
      *(float4*)&Xt[sr][sk + q * 4] = *(const float4*)(src + q * 4);
    #pragma unroll
    for (int j = 0; j < 6; ++j) {
      int idx = tid * 6 + j;
      int rk = idx / 24;
      int c24 = idx - rk * 24;
      int gk = kb * 64 + rk;
      float wv;
      if (c24 < 12) wv = Wg[(size_t)gk * TGT_ + c24];
      else          wv = (gk < 128) ? Wo[(size_t)gk * TGT_ + (c24 - 12)] : 0.f;
      Wt[rk][c24] = wv;
    }
    __syncthreads();
    #pragma unroll 8
    for (int k = 0; k < 64; ++k) {
      float x = Xt[row][k];
      #pragma unroll
      for (int j = 0; j < 6; ++j)
        acc[j] += x * Wt[k][cg * 6 + j];
    }
    __syncthreads();
  }
  #pragma unroll
  for (int j = 0; j < 6; ++j)
    PT[(size_t)(cg * 6 + j) * NODES + node0 + row] = acc[j];
}

// ---------------- readout stage 2 ----------------
__global__ __launch_bounds__(256) void k_readR(const float* __restrict__ PT,
                                               const float* __restrict__ maskR,
                                               const float* __restrict__ bg,
                                               const float* __restrict__ bo,
                                               float* __restrict__ out) {
  __shared__ float red[256];
  const int tid = threadIdx.x;
  const int b = blockIdx.x / TGT_;
  const int t = blockIdx.x - b * TGT_;
  const float bgt = bg[t], bot = bo[t];
  float s = 0.f;
  #pragma unroll
  for (int i = 0; i < 4; ++i) {
    int node = b * N_ + i * 256 + tid;
    float p1 = PT[(size_t)t * NODES + node] + bgt;
    float p2 = PT[(size_t)(12 + t) * NODES + node] + bot;
    s += sigmoidf_(p1) * p2 * maskR[node];
  }
  red[tid] = s;
  __syncthreads();
  #pragma unroll
  for (int off = 128; off > 0; off >>= 1) {
    if (tid < off) red[tid] += red[tid + off];
    __syncthreads();
  }
  if (tid == 0) out[b * TGT_ + t] = red[0];
}

extern "C" void kernel_launch(void* const* d_in, const int* in_sizes, int n_in,
                              void* d_out, int out_size, void* d_ws, size_t ws_size,
                              hipStream_t stream) {
  (void)in_sizes; (void)n_in; (void)out_size; (void)ws_size;
  const float* g    = (const float*)d_in[0];
  const float* h_in = (const float*)d_in[1];
  const int*   e    = (const int*)d_in[2];
  const float* A    = (const float*)d_in[3];
  const float* Wi   = (const float*)d_in[4];
  const float* Wh   = (const float*)d_in[5];
  const float* bi   = (const float*)d_in[6];
  const float* bh   = (const float*)d_in[7];
  const float* Wg   = (const float*)d_in[8];
  const float* bg   = (const float*)d_in[9];
  const float* Wo   = (const float*)d_in[10];
  const float* bo   = (const float*)d_in[11];
  float* out = (float*)d_out;
  float* ws  = (float*)d_ws;

  // workspace layout:
  float* h     = ws;                                   // 1,048,576 f
  float* h0    = h + (size_t)NODES * H_;               // 1,048,576 f
  float* maskA = h0 + (size_t)NODES * H_;              // 8192 f
  float* maskR = maskA + NODES;                        // 8192 f
  unsigned short* X    = (unsigned short*)(maskR + NODES);  // 2,097,152 us (h hi|lo)
  unsigned short* Xm   = X + (size_t)NODES * 256;      // 2,097,152 us (m hi|lo)
  unsigned short* ATh  = Xm + (size_t)NODES * 256;     // 81,920 us
  unsigned short* ATl  = ATh + CAT_ * 128;             // 81,920 us
  unsigned short* WiTh = ATl + CAT_ * 128;             // 49,152 us
  unsigned short* WiTl = WiTh + 384 * 128;             // 49,152 us
  unsigned short* WhTh = WiTl + 384 * 128;             // 49,152 us
  unsigned short* WhTl = WhTh + 384 * 128;             // 49,152 us
  unsigned short* Gb   = WhTl + 384 * 128;             // 8,388,608 us (16.8 MB)
  unsigned char*  Eb   = (unsigned char*)(Gb + (size_t)NODES * N_);   // 8,388,608 u8
  float* aggP = (float*)(Eb + (size_t)NODES * N_);     // KSPLIT * 1,048,576 f (12.6 MB)
  unsigned short* McatT = (unsigned short*)(aggP + (size_t)KSPLIT * NODES * MSG2); // 10.5 MB
  // gates (25.2 MB) overlays aggP(12.6)+McatT(10.5)+2.1MB spare: aggP dead after
  // k_xprep, McatT dead after k_agg_mfma, region past McatT unused.
  float* gates = aggP;
  // PT (24*8192 f = 786 KB) reuses Xm (dead after last k_gates_mfma).
  float* PT = (float*)Xm;

  k_init<<<NODES / 4, 256, 0, stream>>>(h_in, h, h0, X, maskA, maskR);
  k_pack<<<(NODES * N_ / 8) / 256, 256, 0, stream>>>(g, e, Gb, Eb);
  k_aprep<<<(CAT_ * 128 + 255) / 256, 256, 0, stream>>>(A, ATh, ATl);
  k_wprep<<<(2 * 384 * 128 + 255) / 256, 256, 0, stream>>>(Wi, Wh, WiTh, WiTl, WhTh, WhTl);
  for (int layer = 0; layer < NLAYERS_; ++layer) {
    k_gemmT<<<dim3(CAT_ / 128, NODES / 64), 256, 0, stream>>>(X, ATh, ATl, McatT);
    k_agg_mfma<<<(N_ / 64) * 2 * KSPLIT * B_, 256, 0, stream>>>(Gb, Eb, McatT, aggP);
    k_xprep<<<(NODES * MSG2 / 4) / 256, 256, 0, stream>>>(aggP, Xm);
    k_gates_mfma<<<dim3(384 / 128, NODES / 64, 2), 256, 0, stream>>>(Xm, X, WiTh, WiTl, WhTh, WhTl, gates);
    k_gru_elt<<<NODES / 8, 256, 0, stream>>>(gates, bi, bh, maskA, h, X);
  }
  k_readP<<<NODES / 64, 256, 0, stream>>>(h, h0, Wg, Wo, PT);
  k_readR<<<B_ * TGT_, 256, 0, stream>>>(PT, maskR, bg, bo, out);
}

// Round 16
// 239.906 us; speedup vs baseline: 1.0743x; 1.0743x over previous
//
#include <hip/hip_runtime.h>

#define B_      8
#define N_      1024
#define DIN_    64
#define H_      128
#define MSG2    128
#define L_      5
#define TGT_    12
#define NLAYERS_ 3
#define CAT_    640          // L_ * MSG2
#define NODES   (B_ * N_)    // 8192
#define KSPLIT  2
#define NT_     16           // k-tiles per block (512 k / 32)

typedef __attribute__((ext_vector_type(8))) short s16x8;
typedef __attribute__((ext_vector_type(4))) float f32x4;

#define GLD16(G, L) __builtin_amdgcn_global_load_lds( \
    (const __attribute__((address_space(1))) void*)(G), \
    (__attribute__((address_space(3))) void*)(L), 16, 0, 0)

__device__ __forceinline__ float sigmoidf_(float x) { return 1.f / (1.f + __expf(-x)); }

__device__ __forceinline__ unsigned short f2bf(float x) {
  unsigned int u = __float_as_uint(x);
  u += 0x7FFFu + ((u >> 16) & 1u);      // round-to-nearest-even
  return (unsigned short)(u >> 16);
}
__device__ __forceinline__ float bf2f(unsigned short u) {
  return __uint_as_float(((unsigned int)u) << 16);
}

// ---------------- init: pad h_in -> h0/h (fp32), X=h hi/lo bf16, masks ----------------
__global__ __launch_bounds__(256) void k_init(const float* __restrict__ h_in,
                                              float* __restrict__ h,
                                              float* __restrict__ h0,
                                              unsigned short* __restrict__ X,
                                              float* __restrict__ maskA,
                                              float* __restrict__ maskR) {
  int node = blockIdx.x * 4 + (threadIdx.x >> 6);
  int lane = threadIdx.x & 63;
  float v = h_in[(size_t)node * DIN_ + lane];
  size_t base = (size_t)node * H_;
  h[base + lane] = v;   h[base + 64 + lane] = 0.f;
  h0[base + lane] = v;  h0[base + 64 + lane] = 0.f;
  unsigned short hi = f2bf(v);
  unsigned short lo = f2bf(v - bf2f(hi));
  size_t xb = (size_t)node * 256;
  X[xb + lane] = hi;        X[xb + 64 + lane] = 0;
  X[xb + 128 + lane] = lo;  X[xb + 192 + lane] = 0;
  float sa = fabsf(v), ss = v;
  for (int off = 32; off > 0; off >>= 1) {
    sa += __shfl_down(sa, off);
    ss += __shfl_down(ss, off);
  }
  if (lane == 0) {
    maskA[node] = (sa > 0.f) ? 1.f : 0.f;
    maskR[node] = (ss > 0.f) ? 1.f : 0.f;
  }
}

// ---------------- pack: Gb = bf16(g), Eb = u8(e)  (once) ----------------
__global__ __launch_bounds__(256) void k_pack(const float* __restrict__ g,
                                              const int* __restrict__ e,
                                              unsigned short* __restrict__ Gb,
                                              unsigned char* __restrict__ Eb) {
  size_t i8 = ((size_t)blockIdx.x * 256 + threadIdx.x) * 8;
  float4 g0 = *(const float4*)&g[i8];
  float4 g1 = *(const float4*)&g[i8 + 4];
  int4   e0 = *(const int4*)&e[i8];
  int4   e1 = *(const int4*)&e[i8 + 4];
  ushort4 ga, gb;
  ga.x = f2bf(g0.x); ga.y = f2bf(g0.y); ga.z = f2bf(g0.z); ga.w = f2bf(g0.w);
  gb.x = f2bf(g1.x); gb.y = f2bf(g1.y); gb.z = f2bf(g1.z); gb.w = f2bf(g1.w);
  *(ushort4*)&Gb[i8]     = ga;
  *(ushort4*)&Gb[i8 + 4] = gb;
  uint2 ev;
  ev.x = (unsigned)(e0.x & 0xFF) | ((unsigned)(e0.y & 0xFF) << 8) |
         ((unsigned)(e0.z & 0xFF) << 16) | ((unsigned)(e0.w & 0xFF) << 24);
  ev.y = (unsigned)(e1.x & 0xFF) | ((unsigned)(e1.y & 0xFF) << 8) |
         ((unsigned)(e1.z & 0xFF) << 16) | ((unsigned)(e1.w & 0xFF) << 24);
  *(uint2*)&Eb[i8] = ev;
}

// ---------------- aprep: ATh/ATl[c][d] = bf16 hi/lo of A[l][d][o], c=l*128+o ----------------
__global__ __launch_bounds__(256) void k_aprep(const float* __restrict__ A,
                                               unsigned short* __restrict__ ATh,
                                               unsigned short* __restrict__ ATl) {
  int idx = blockIdx.x * 256 + threadIdx.x;
  if (idx >= CAT_ * 128) return;
  int c = idx >> 7, d = idx & 127;
  int l = c >> 7, o = c & 127;
  float v = A[((size_t)l * 128 + d) * 128 + o];
  unsigned short hi = f2bf(v);
  ATh[idx] = hi;
  ATl[idx] = f2bf(v - bf2f(hi));
}

// ---------------- wprep: W{i,h}T hi/lo [c][k] bf16 (transposed) ----------------
__global__ __launch_bounds__(256) void k_wprep(const float* __restrict__ Wi,
                                               const float* __restrict__ Wh,
                                               unsigned short* __restrict__ WiTh,
                                               unsigned short* __restrict__ WiTl,
                                               unsigned short* __restrict__ WhTh,
                                               unsigned short* __restrict__ WhTl) {
  int idx = blockIdx.x * 256 + threadIdx.x;
  if (idx < 384 * 128) {
    int c = idx >> 7, k = idx & 127;
    float v = Wi[(size_t)k * 384 + c];
    unsigned short hi = f2bf(v);
    WiTh[idx] = hi; WiTl[idx] = f2bf(v - bf2f(hi));
  } else if (idx < 2 * 384 * 128) {
    int i = idx - 384 * 128;
    int c = i >> 7, k = i & 127;
    float v = Wh[(size_t)k * 384 + c];
    unsigned short hi = f2bf(v);
    WhTh[i] = hi; WhTl[i] = f2bf(v - bf2f(hi));
  }
}

// ---------------- McatT[b][l][o][w] via split-precision bf16 MFMA ----------------
__global__ __launch_bounds__(256) void k_gemmT(const unsigned short* __restrict__ X,
                                               const unsigned short* __restrict__ ATh,
                                               const unsigned short* __restrict__ ATl,
                                               unsigned short* __restrict__ McatT) {
  __shared__ __align__(16) unsigned short Ah[64 * 40];
  __shared__ __align__(16) unsigned short Al[64 * 40];
  __shared__ __align__(16) unsigned short Bh[128 * 40];
  __shared__ __align__(16) unsigned short Bl2[128 * 40];
  const int tid = threadIdx.x;
  const int c0 = blockIdx.x * 128;
  const int node0 = blockIdx.y * 64;
  const int b = node0 >> 10;
  const int w0 = node0 & 1023;
  const int wid = tid >> 6, lane = tid & 63;
  const int wr = wid >> 1, wc = wid & 1;
  const int lr = lane & 15, lg = lane >> 4;
  const int ar = tid >> 2, aq = (tid & 3) * 8;
  const int br = tid >> 1, bq = (tid & 1) * 16;
  f32x4 acc[2][4];
  #pragma unroll
  for (int m = 0; m < 2; ++m)
    #pragma unroll
    for (int n = 0; n < 4; ++n) acc[m][n] = {0.f, 0.f, 0.f, 0.f};
  for (int kk = 0; kk < 4; ++kk) {
    const int kb = kk * 32;
    *(uint4*)&Ah[ar * 40 + aq] = *(const uint4*)&X[(size_t)(node0 + ar) * 256 + kb + aq];
    *(uint4*)&Al[ar * 40 + aq] = *(const uint4*)&X[(size_t)(node0 + ar) * 256 + 128 + kb + aq];
    const unsigned short* bh = ATh + (size_t)(c0 + br) * 128 + kb + bq;
    const unsigned short* bl = ATl + (size_t)(c0 + br) * 128 + kb + bq;
    *(uint4*)&Bh[br * 40 + bq]      = *(const uint4*)bh;
    *(uint4*)&Bh[br * 40 + bq + 8]  = *(const uint4*)(bh + 8);
    *(uint4*)&Bl2[br * 40 + bq]     = *(const uint4*)bl;
    *(uint4*)&Bl2[br * 40 + bq + 8] = *(const uint4*)(bl + 8);
    __syncthreads();
    s16x8 ah[2], al[2], bhf[4], blf[4];
    #pragma unroll
    for (int m = 0; m < 2; ++m) {
      int row = (wr * 32 + m * 16 + lr) * 40 + lg * 8;
      ah[m] = *(const s16x8*)&Ah[row];
      al[m] = *(const s16x8*)&Al[row];
    }
    #pragma unroll
    for (int n = 0; n < 4; ++n) {
      int row = (wc * 64 + n * 16 + lr) * 40 + lg * 8;
      bhf[n] = *(const s16x8*)&Bh[row];
      blf[n] = *(const s16x8*)&Bl2[row];
    }
    #pragma unroll
    for (int m = 0; m < 2; ++m)
      #pragma unroll
      for (int n = 0; n < 4; ++n) {
        acc[m][n] = __builtin_amdgcn_mfma_f32_16x16x32_bf16(ah[m], bhf[n], acc[m][n], 0, 0, 0);
        acc[m][n] = __builtin_amdgcn_mfma_f32_16x16x32_bf16(ah[m], blf[n], acc[m][n], 0, 0, 0);
        acc[m][n] = __builtin_amdgcn_mfma_f32_16x16x32_bf16(al[m], bhf[n], acc[m][n], 0, 0, 0);
      }
    __syncthreads();
  }
  #pragma unroll
  for (int m = 0; m < 2; ++m)
    #pragma unroll
    for (int n = 0; n < 4; ++n) {
      int c = c0 + wc * 64 + n * 16 + lr;
      int l = c >> 7, o = c & 127;
      int w = w0 + wr * 32 + m * 16 + lg * 4;
      ushort4 v;
      v.x = f2bf(acc[m][n][0]); v.y = f2bf(acc[m][n][1]);
      v.z = f2bf(acc[m][n][2]); v.w = f2bf(acc[m][n][3]);
      *(ushort4*)&McatT[(((size_t)b * L_ + l) * MSG2 + o) * N_ + w] = v;
    }
}

// ---------------- agg via 5 masked bf16 MFMA GEMMs ----------------
// 64v x 64o tile, KSPLIT=2 (grid 512 = 2 blocks/CU), XOR-swizzled LDS.
// T4 counted-vmcnt pipeline: 3 LDS buffers, loads issued 2 tiles ahead via
// global_load_lds; per tile: s_waitcnt vmcnt(7) (tile T lands, T+1 stays in
// flight) -> ds_write Et -> lgkmcnt(0)+s_barrier -> issue T+2 -> compute T.
// Race safety: buf (T+2)%3's prior tenant (tile T-1) readers are ordered by
// the iter-T barrier before the write-issue. Et double-buffered by parity.
// Addressing identical to r15 (refcheck-verified).
__global__ __launch_bounds__(256, 2) void k_agg_mfma(const unsigned short* __restrict__ Gb,
                                                     const unsigned char* __restrict__ Eb,
                                                     const unsigned short* __restrict__ McatT,
                                                     float* __restrict__ aggP) {
  __shared__ __align__(16) unsigned short GtS[3][64 * 32];      // 3 x 4 KB
  __shared__ __align__(16) unsigned short BlS[3][L_][64 * 32];  // 3 x 20 KB
  __shared__ __align__(16) unsigned char  EtS[2][64 * 40];      // 2 x 2.5 KB
  char* GtB = (char*)GtS;   // buffer stride 4096 B
  char* BlB = (char*)BlS;   // buffer stride 20480 B, label stride 4096 B
  char* EtB = (char*)EtS;   // buffer stride 2560 B

  const int tid = threadIdx.x;
  // XCD grouping: 32 blocks sharing (ks,b) -> same XCD (Mcat L2 reuse).
  const int fid = blockIdx.x;          // 0..511
  const int xcd = fid & 7;
  const int s   = fid >> 3;            // 0..63
  const int p   = xcd * 2 + (s >> 5);  // (ks,b) pair 0..15
  const int idx = s & 31;
  const int v0  = (idx & 15) * 64;
  const int oh  = idx >> 4;            // o-half 0/1
  const int ks  = p >> 3;              // 0..1
  const int b   = p & 7;

  const int wid  = tid >> 6, lane = tid & 63;
  const int wr   = wid >> 1, wc = wid & 1;    // wave tile 32v x 32o
  const int lr   = lane & 15, lg = lane >> 4;

  f32x4 acc[2][2];
  #pragma unroll
  for (int m = 0; m < 2; ++m)
    #pragma unroll
    for (int n = 0; n < 2; ++n) acc[m][n] = {0.f, 0.f, 0.f, 0.f};

  const int ar = tid >> 2, aq = (tid & 3) * 8;
  // inverse-swizzle source mapping for linear dest slot (verified r15):
  const int rsrc = ar ^ ((ar >> 2) & 1);
  const int kq   = aq ^ ((rsrc & 3) << 3);
  const size_t garow  = ((size_t)b * N_ + v0 + ar) * N_;        // Eb source
  const size_t garowS = ((size_t)b * N_ + v0 + rsrc) * N_;      // gload source
  const size_t mrowS  = (((size_t)b * L_) * MSG2 + oh * 64 + rsrc) * N_;
  const size_t lstep  = (size_t)MSG2 * N_;
  const int ksbase = ks * 512;

  const int ldst = tid * 16;
  const int et_w = ar * 40 + aq;
  const int fsw  = (lr & 7) << 4;

#define ISSUE(T) { \
    const int kb_ = ksbase + (T) * 32; \
    const int nb_ = (T) % 3; \
    GLD16(Gb + garowS + kb_ + kq, GtB + nb_ * 4096 + ldst); \
    _Pragma("unroll") \
    for (int l_ = 0; l_ < L_; ++l_) \
      GLD16(McatT + mrowS + (size_t)l_ * lstep + kb_ + kq, \
            BlB + nb_ * 20480 + l_ * 4096 + ldst); }

#define COMPUTE(T) { \
    const char* Gc = GtB + ((T) % 3) * 4096; \
    const char* Bc = BlB + ((T) % 3) * 20480; \
    const char* Ec = EtB + ((T) & 1) * 2560; \
    s16x8 gt[2]; uint2 et[2]; \
    _Pragma("unroll") \
    for (int m = 0; m < 2; ++m) { \
      int row_ = wr * 32 + m * 16 + lr; \
      gt[m] = *(const s16x8*)(Gc + ((row_ * 64 + lg * 16) ^ fsw)); \
      et[m] = *(const uint2*)(Ec + row_ * 40 + lg * 8); \
    } \
    _Pragma("unroll") \
    for (int l_ = 0; l_ < L_; ++l_) { \
      s16x8 bfr[2]; \
      _Pragma("unroll") \
      for (int n = 0; n < 2; ++n) { \
        int row_ = wc * 32 + n * 16 + lr; \
        bfr[n] = *(const s16x8*)(Bc + l_ * 4096 + ((row_ * 64 + lg * 16) ^ fsw)); \
      } \
      _Pragma("unroll") \
      for (int m = 0; m < 2; ++m) { \
        unsigned int w0e = et[m].x, w1e = et[m].y; \
        s16x8 af; \
        af[0] = (((w0e      ) & 0xFFu) == (unsigned)l_) ? gt[m][0] : (short)0; \
        af[1] = (((w0e >>  8) & 0xFFu) == (unsigned)l_) ? gt[m][1] : (short)0; \
        af[2] = (((w0e >> 16) & 0xFFu) == (unsigned)l_) ? gt[m][2] : (short)0; \
        af[3] = (((w0e >> 24) & 0xFFu) == (unsigned)l_) ? gt[m][3] : (short)0; \
        af[4] = (((w1e      ) & 0xFFu) == (unsigned)l_) ? gt[m][4] : (short)0; \
        af[5] = (((w1e >>  8) & 0xFFu) == (unsigned)l_) ? gt[m][5] : (short)0; \
        af[6] = (((w1e >> 16) & 0xFFu) == (unsigned)l_) ? gt[m][6] : (short)0; \
        af[7] = (((w1e >> 24) & 0xFFu) == (unsigned)l_) ? gt[m][7] : (short)0; \
        _Pragma("unroll") \
        for (int n = 0; n < 2; ++n) \
          acc[m][n] = __builtin_amdgcn_mfma_f32_16x16x32_bf16(af, bfr[n], acc[m][n], 0, 0, 0); \
      } \
    } }

#define STEP(T, EV) { \
    if ((T) + 1 < NT_) asm volatile("s_waitcnt vmcnt(7)" ::: "memory"); \
    else               asm volatile("s_waitcnt vmcnt(0)" ::: "memory"); \
    *(uint2*)(EtB + ((T) & 1) * 2560 + et_w) = EV; \
    asm volatile("s_waitcnt lgkmcnt(0)" ::: "memory"); \
    __builtin_amdgcn_s_barrier(); \
    if ((T) + 2 < NT_) { \
      ISSUE((T) + 2); \
      EV = *(const uint2*)&Eb[garow + ksbase + ((T) + 2) * 32 + aq]; \
    } \
    COMPUTE(T); }

  // prologue: issue tiles 0,1 (each 6 gloads + 1 Eb load = 7 vmem ops)
  uint2 evA, evB;
  ISSUE(0);
  evA = *(const uint2*)&Eb[garow + ksbase + aq];
  ISSUE(1);
  evB = *(const uint2*)&Eb[garow + ksbase + 32 + aq];

  for (int t2 = 0; t2 < NT_; t2 += 2) {
    STEP(t2, evA);
    STEP(t2 + 1, evB);
  }
#undef ISSUE
#undef COMPUTE
#undef STEP

  float* op = aggP + ((size_t)ks * NODES + (size_t)b * N_ + v0) * MSG2 + oh * 64;
  #pragma unroll
  for (int m = 0; m < 2; ++m)
    #pragma unroll
    for (int n = 0; n < 2; ++n)
      #pragma unroll
      for (int j = 0; j < 4; ++j) {
        int row = wr * 32 + m * 16 + lg * 4 + j;
        int col = wc * 32 + n * 16 + lr;
        op[(size_t)row * MSG2 + col] = acc[m][n][j];
      }
}

// ---------------- xprep: Xm = hi/lo bf16 of summed agg slabs (KSPLIT=2) ----------------
__global__ __launch_bounds__(256) void k_xprep(const float* __restrict__ aggP,
                                               unsigned short* __restrict__ Xm) {
  const size_t slab = (size_t)NODES * MSG2;
  size_t i4 = ((size_t)blockIdx.x * 256 + threadIdx.x) * 4;
  float4 s;
  s.x = 0.f; s.y = 0.f; s.z = 0.f; s.w = 0.f;
  #pragma unroll
  for (int k = 0; k < KSPLIT; ++k) {
    float4 v = *(const float4*)&aggP[k * slab + i4];
    s.x += v.x; s.y += v.y; s.z += v.z; s.w += v.w;
  }
  size_t node = i4 >> 7;
  size_t j = i4 & 127;
  ushort4 hi, lo;
  hi.x = f2bf(s.x); lo.x = f2bf(s.x - bf2f(hi.x));
  hi.y = f2bf(s.y); lo.y = f2bf(s.y - bf2f(hi.y));
  hi.z = f2bf(s.z); lo.z = f2bf(s.z - bf2f(hi.z));
  hi.w = f2bf(s.w); lo.w = f2bf(s.w - bf2f(hi.w));
  *(ushort4*)&Xm[node * 256 + j]       = hi;
  *(ushort4*)&Xm[node * 256 + 128 + j] = lo;
}

// ---------------- gates via split-precision bf16 MFMA ----------------
__global__ __launch_bounds__(256) void k_gates_mfma(const unsigned short* __restrict__ Xm,
                                                    const unsigned short* __restrict__ Xh,
                                                    const unsigned short* __restrict__ WiTh,
                                                    const unsigned short* __restrict__ WiTl,
                                                    const unsigned short* __restrict__ WhTh,
                                                    const unsigned short* __restrict__ WhTl,
                                                    float* __restrict__ gates) {
  __shared__ __align__(16) unsigned short Ah[64 * 40];
  __shared__ __align__(16) unsigned short Al[64 * 40];
  __shared__ __align__(16) unsigned short Bh[128 * 40];
  __shared__ __align__(16) unsigned short Bl2[128 * 40];
  const int tid = threadIdx.x;
  const int z = blockIdx.z;
  const unsigned short* Xp  = z ? Xh : Xm;
  const unsigned short* WTh = z ? WhTh : WiTh;
  const unsigned short* WTl = z ? WhTl : WiTl;
  const int c0 = blockIdx.x * 128;
  const int node0 = blockIdx.y * 64;
  const int wid = tid >> 6, lane = tid & 63;
  const int wr = wid >> 1, wc = wid & 1;
  const int lr = lane & 15, lg = lane >> 4;
  const int ar = tid >> 2, aq = (tid & 3) * 8;
  const int br = tid >> 1, bq = (tid & 1) * 16;
  f32x4 acc[2][4];
  #pragma unroll
  for (int m = 0; m < 2; ++m)
    #pragma unroll
    for (int n = 0; n < 4; ++n) acc[m][n] = {0.f, 0.f, 0.f, 0.f};
  for (int kk = 0; kk < 4; ++kk) {
    const int kb = kk * 32;
    *(uint4*)&Ah[ar * 40 + aq] = *(const uint4*)&Xp[(size_t)(node0 + ar) * 256 + kb + aq];
    *(uint4*)&Al[ar * 40 + aq] = *(const uint4*)&Xp[(size_t)(node0 + ar) * 256 + 128 + kb + aq];
    const unsigned short* bh = WTh + (size_t)(c0 + br) * 128 + kb + bq;
    const unsigned short* bl = WTl + (size_t)(c0 + br) * 128 + kb + bq;
    *(uint4*)&Bh[br * 40 + bq]      = *(const uint4*)bh;
    *(uint4*)&Bh[br * 40 + bq + 8]  = *(const uint4*)(bh + 8);
    *(uint4*)&Bl2[br * 40 + bq]     = *(const uint4*)bl;
    *(uint4*)&Bl2[br * 40 + bq + 8] = *(const uint4*)(bl + 8);
    __syncthreads();
    s16x8 ah[2], al[2], bhf[4], blf[4];
    #pragma unroll
    for (int m = 0; m < 2; ++m) {
      int row = (wr * 32 + m * 16 + lr) * 40 + lg * 8;
      ah[m] = *(const s16x8*)&Ah[row];
      al[m] = *(const s16x8*)&Al[row];
    }
    #pragma unroll
    for (int n = 0; n < 4; ++n) {
      int row = (wc * 64 + n * 16 + lr) * 40 + lg * 8;
      bhf[n] = *(const s16x8*)&Bh[row];
      blf[n] = *(const s16x8*)&Bl2[row];
    }
    #pragma unroll
    for (int m = 0; m < 2; ++m)
      #pragma unroll
      for (int n = 0; n < 4; ++n) {
        acc[m][n] = __builtin_amdgcn_mfma_f32_16x16x32_bf16(ah[m], bhf[n], acc[m][n], 0, 0, 0);
        acc[m][n] = __builtin_amdgcn_mfma_f32_16x16x32_bf16(ah[m], blf[n], acc[m][n], 0, 0, 0);
        acc[m][n] = __builtin_amdgcn_mfma_f32_16x16x32_bf16(al[m], bhf[n], acc[m][n], 0, 0, 0);
      }
    __syncthreads();
  }
  #pragma unroll
  for (int m = 0; m < 2; ++m)
    #pragma unroll
    for (int n = 0; n < 4; ++n) {
      int c = c0 + wc * 64 + n * 16 + lr;
      int row = node0 + wr * 32 + m * 16 + lg * 4;
      #pragma unroll
      for (int j = 0; j < 4; ++j)
        gates[(size_t)(row + j) * 768 + z * 384 + c] = acc[m][n][j];
    }
}

// ---------------- GRU elementwise (+ X hi/lo write) ----------------
__global__ __launch_bounds__(256) void k_gru_elt(const float* __restrict__ gates,
                                                 const float* __restrict__ bi,
                                                 const float* __restrict__ bh,
                                                 const float* __restrict__ maskA,
                                                 float* __restrict__ h,
                                                 unsigned short* __restrict__ X) {
  const int t = threadIdx.x;
  const int node = blockIdx.x * 8 + (t >> 5);
  const int j4 = (t & 31) * 4;
  const size_t gb = (size_t)node * 768;
  float4 gir = *(const float4*)&gates[gb + j4];
  float4 giz = *(const float4*)&gates[gb + 128 + j4];
  float4 gin = *(const float4*)&gates[gb + 256 + j4];
  float4 ghr = *(const float4*)&gates[gb + 384 + j4];
  float4 ghz = *(const float4*)&gates[gb + 512 + j4];
  float4 ghn = *(const float4*)&gates[gb + 640 + j4];
  float4 bir = *(const float4*)&bi[j4];
  float4 biz = *(const float4*)&bi[128 + j4];
  float4 bin = *(const float4*)&bi[256 + j4];
  float4 bhr = *(const float4*)&bh[j4];
  float4 bhz = *(const float4*)&bh[128 + j4];
  float4 bhn = *(const float4*)&bh[256 + j4];
  float4 hv = *(const float4*)&h[(size_t)node * 128 + j4];
  float m = maskA[node];
  float4 ho;
  {
    float r = sigmoidf_(gir.x + bir.x + ghr.x + bhr.x);
    float z = sigmoidf_(giz.x + biz.x + ghz.x + bhz.x);
    float nn = tanhf(gin.x + bin.x + r * (ghn.x + bhn.x));
    ho.x = ((1.f - z) * nn + z * hv.x) * m;
  }
  {
    float r = sigmoidf_(gir.y + bir.y + ghr.y + bhr.y);
    float z = sigmoidf_(giz.y + biz.y + ghz.y + bhz.y);
    float nn = tanhf(gin.y + bin.y + r * (ghn.y + bhn.y));
    ho.y = ((1.f - z) * nn + z * hv.y) * m;
  }
  {
    float r = sigmoidf_(gir.z + bir.z + ghr.z + bhr.z);
    float z = sigmoidf_(giz.z + biz.z + ghz.z + bhz.z);
    float nn = tanhf(gin.z + bin.z + r * (ghn.z + bhn.z));
    ho.z = ((1.f - z) * nn + z * hv.z) * m;
  }
  {
    float r = sigmoidf_(gir.w + bir.w + ghr.w + bhr.w);
    float z = sigmoidf_(giz.w + biz.w + ghz.w + bhz.w);
    float nn = tanhf(gin.w + bin.w + r * (ghn.w + bhn.w));
    ho.w = ((1.f - z) * nn + z * hv.w) * m;
  }
  *(float4*)&h[(size_t)node * 128 + j4] = ho;
  ushort4 hi, lo;
  hi.x = f2bf(ho.x); lo.x = f2bf(ho.x - bf2f(hi.x));
  hi.y = f2bf(ho.y); lo.y = f2bf(ho.y - bf2f(hi.y));
  hi.z = f2bf(ho.z); lo.z = f2bf(ho.z - bf2f(hi.z));
  hi.w = f2bf(ho.w); lo.w = f2bf(ho.w - bf2f(hi.w));
  *(ushort4*)&X[(size_t)node * 256 + j4]       = hi;
  *(ushort4*)&X[(size_t)node * 256 + 128 + j4] = lo;
}

// ---------------- readout stage 1: PT[c][node] = ([hT,h0] @ Wcat)[node][c] ----------------
__global__ __launch_bounds__(256) void k_readP(const float* __restrict__ h,
                                               const float* __restrict__ h0,
                                               const float* __restrict__ Wg,
                                               const float* __restrict__ Wo,
                                               float* __restrict__ PT) {
  __shared__ float Xt[64][65];
  __shared__ float Wt[64][25];
  const int tid = threadIdx.x;
  const int node0 = blockIdx.x * 64;
  const int row = tid >> 2;
  const int cg  = tid & 3;
  float acc[6] = {0.f, 0.f, 0.f, 0.f, 0.f, 0.f};
  const int sr = tid >> 2;
  const int sk = (tid & 3) * 16;
  #pragma unroll
  for (int kb = 0; kb < 4; ++kb) {
    const float* src = (kb < 2 ? h : h0) + (size_t)(node0 + sr) * 128 + (kb & 1) * 64 + sk;
    #pragma unroll
    for (int q = 0; q < 4; ++q)
      *(float4*)&Xt[sr][sk + q * 4] = *(const float4*)(src + q * 4);
    #pragma unroll
    for (int j = 0; j < 6; ++j) {
      int idx = tid * 6 + j;
      int rk = idx / 24;
      int c24 = idx - rk * 24;
      int gk = kb * 64 + rk;
      float wv;
      if (c24 < 12) wv = Wg[(size_t)gk * TGT_ + c24];
      else          wv = (gk < 128) ? Wo[(size_t)gk * TGT_ + (c24 - 12)] : 0.f;
      Wt[rk][c24] = wv;
    }
    __syncthreads();
    #pragma unroll 8
    for (int k = 0; k < 64; ++k) {
      float x = Xt[row][k];
      #pragma unroll
      for (int j = 0; j < 6; ++j)
        acc[j] += x * Wt[k][cg * 6 + j];
    }
    __syncthreads();
  }
  #pragma unroll
  for (int j = 0; j < 6; ++j)
    PT[(size_t)(cg * 6 + j) * NODES + node0 + row] = acc[j];
}

// ---------------- readout stage 2 ----------------
__global__ __launch_bounds__(256) void k_readR(const float* __restrict__ PT,
                                               const float* __restrict__ maskR,
                                               const float* __restrict__ bg,
                                               const float* __restrict__ bo,
                                               float* __restrict__ out) {
  __shared__ float red[256];
  const int tid = threadIdx.x;
  const int b = blockIdx.x / TGT_;
  const int t = blockIdx.x - b * TGT_;
  const float bgt = bg[t], bot = bo[t];
  float s = 0.f;
  #pragma unroll
  for (int i = 0; i < 4; ++i) {
    int node = b * N_ + i * 256 + tid;
    float p1 = PT[(size_t)t * NODES + node] + bgt;
    float p2 = PT[(size_t)(12 + t) * NODES + node] + bot;
    s += sigmoidf_(p1) * p2 * maskR[node];
  }
  red[tid] = s;
  __syncthreads();
  #pragma unroll
  for (int off = 128; off > 0; off >>= 1) {
    if (tid < off) red[tid] += red[tid + off];
    __syncthreads();
  }
  if (tid == 0) out[b * TGT_ + t] = red[0];
}

extern "C" void kernel_launch(void* const* d_in, const int* in_sizes, int n_in,
                              void* d_out, int out_size, void* d_ws, size_t ws_size,
                              hipStream_t stream) {
  (void)in_sizes; (void)n_in; (void)out_size; (void)ws_size;
  const float* g    = (const float*)d_in[0];
  const float* h_in = (const float*)d_in[1];
  const int*   e    = (const int*)d_in[2];
  const float* A    = (const float*)d_in[3];
  const float* Wi   = (const float*)d_in[4];
  const float* Wh   = (const float*)d_in[5];
  const float* bi   = (const float*)d_in[6];
  const float* bh   = (const float*)d_in[7];
  const float* Wg   = (const float*)d_in[8];
  const float* bg   = (const float*)d_in[9];
  const float* Wo   = (const float*)d_in[10];
  const float* bo   = (const float*)d_in[11];
  float* out = (float*)d_out;
  float* ws  = (float*)d_ws;

  // workspace layout:
  float* h     = ws;                                   // 1,048,576 f
  float* h0    = h + (size_t)NODES * H_;               // 1,048,576 f
  float* maskA = h0 + (size_t)NODES * H_;              // 8192 f
  float* maskR = maskA + NODES;                        // 8192 f
  unsigned short* X    = (unsigned short*)(maskR + NODES);  // 2,097,152 us (h hi|lo)
  unsigned short* Xm   = X + (size_t)NODES * 256;      // 2,097,152 us (m hi|lo)
  unsigned short* ATh  = Xm + (size_t)NODES * 256;     // 81,920 us
  unsigned short* ATl  = ATh + CAT_ * 128;             // 81,920 us
  unsigned short* WiTh = ATl + CAT_ * 128;             // 49,152 us
  unsigned short* WiTl = WiTh + 384 * 128;             // 49,152 us
  unsigned short* WhTh = WiTl + 384 * 128;             // 49,152 us
  unsigned short* WhTl = WhTh + 384 * 128;             // 49,152 us
  unsigned short* Gb   = WhTl + 384 * 128;             // 8,388,608 us (16.8 MB)
  unsigned char*  Eb   = (unsigned char*)(Gb + (size_t)NODES * N_);   // 8,388,608 u8
  float* aggP = (float*)(Eb + (size_t)NODES * N_);     // KSPLIT * 1,048,576 f (8.4 MB)
  unsigned short* McatT = (unsigned short*)(aggP + (size_t)KSPLIT * NODES * MSG2); // 10.5 MB
  // gates (25.2 MB) overlays aggP(8.4)+McatT(10.5)+unused ws beyond: aggP dead
  // after k_xprep, McatT dead after k_agg_mfma, tail region otherwise unused.
  float* gates = aggP;
  // PT (24*8192 f = 786 KB) reuses Xm (dead after last k_gates_mfma).
  float* PT = (float*)Xm;

  k_init<<<NODES / 4, 256, 0, stream>>>(h_in, h, h0, X, maskA, maskR);
  k_pack<<<(NODES * N_ / 8) / 256, 256, 0, stream>>>(g, e, Gb, Eb);
  k_aprep<<<(CAT_ * 128 + 255) / 256, 256, 0, stream>>>(A, ATh, ATl);
  k_wprep<<<(2 * 384 * 128 + 255) / 256, 256, 0, stream>>>(Wi, Wh, WiTh, WiTl, WhTh, WhTl);
  for (int layer = 0; layer < NLAYERS_; ++layer) {
    k_gemmT<<<dim3(CAT_ / 128, NODES / 64), 256, 0, stream>>>(X, ATh, ATl, McatT);
    k_agg_mfma<<<(N_ / 64) * 2 * KSPLIT * B_, 256, 0, stream>>>(Gb, Eb, McatT, aggP);
    k_xprep<<<(NODES * MSG2 / 4) / 256, 256, 0, stream>>>(aggP, Xm);
    k_gates_mfma<<<dim3(384 / 128, NODES / 64, 2), 256, 0, stream>>>(Xm, X, WiTh, WiTl, WhTh, WhTl, gates);
    k_gru_elt<<<NODES / 8, 256, 0, stream>>>(gates, bi, bh, maskA, h, X);
  }
  k_readP<<<NODES / 64, 256, 0, stream>>>(h, h0, Wg, Wo, PT);
  k_readR<<<B_ * TGT_, 256, 0, stream>>>(PT, maskR, bg, bo, out);
}

// Round 17
// 220.757 us; speedup vs baseline: 1.1675x; 1.0867x over previous
//
#include <hip/hip_runtime.h>

#define B_      8
#define N_      1024
#define DIN_    64
#define H_      128
#define MSG2    128
#define L_      5
#define TGT_    12
#define NLAYERS_ 3
#define CAT_    640          // L_ * MSG2
#define NODES   (B_ * N_)    // 8192
#define KSPLIT  4

typedef __attribute__((ext_vector_type(8))) short s16x8;
typedef __attribute__((ext_vector_type(4))) float f32x4;

__device__ __forceinline__ float sigmoidf_(float x) { return 1.f / (1.f + __expf(-x)); }

__device__ __forceinline__ unsigned short f2bf(float x) {
  unsigned int u = __float_as_uint(x);
  u += 0x7FFFu + ((u >> 16) & 1u);      // round-to-nearest-even
  return (unsigned short)(u >> 16);
}
__device__ __forceinline__ float bf2f(unsigned short u) {
  return __uint_as_float(((unsigned int)u) << 16);
}

// ---------------- merged prep: init (blocks 0..2047) | aprep (2048..2367) | wprep (2368..2751) ----------------
__global__ __launch_bounds__(256) void k_prep(const float* __restrict__ h_in,
                                              const float* __restrict__ A,
                                              const float* __restrict__ Wi,
                                              const float* __restrict__ Wh,
                                              float* __restrict__ h,
                                              float* __restrict__ h0,
                                              unsigned short* __restrict__ X,
                                              float* __restrict__ maskA,
                                              float* __restrict__ maskR,
                                              unsigned short* __restrict__ ATh,
                                              unsigned short* __restrict__ ATl,
                                              unsigned short* __restrict__ WiTh,
                                              unsigned short* __restrict__ WiTl,
                                              unsigned short* __restrict__ WhTh,
                                              unsigned short* __restrict__ WhTl) {
  const int blk = blockIdx.x;
  if (blk < NODES / 4) {
    int node = blk * 4 + (threadIdx.x >> 6);
    int lane = threadIdx.x & 63;
    float v = h_in[(size_t)node * DIN_ + lane];
    size_t base = (size_t)node * H_;
    h[base + lane] = v;   h[base + 64 + lane] = 0.f;
    h0[base + lane] = v;  h0[base + 64 + lane] = 0.f;
    unsigned short hi = f2bf(v);
    unsigned short lo = f2bf(v - bf2f(hi));
    size_t xb = (size_t)node * 256;
    X[xb + lane] = hi;        X[xb + 64 + lane] = 0;
    X[xb + 128 + lane] = lo;  X[xb + 192 + lane] = 0;
    float sa = fabsf(v), ss = v;
    for (int off = 32; off > 0; off >>= 1) {
      sa += __shfl_down(sa, off);
      ss += __shfl_down(ss, off);
    }
    if (lane == 0) {
      maskA[node] = (sa > 0.f) ? 1.f : 0.f;
      maskR[node] = (ss > 0.f) ? 1.f : 0.f;
    }
  } else if (blk < NODES / 4 + (CAT_ * 128) / 256) {
    int idx = (blk - NODES / 4) * 256 + threadIdx.x;
    int c = idx >> 7, d = idx & 127;
    int l = c >> 7, o = c & 127;
    float v = A[((size_t)l * 128 + d) * 128 + o];
    unsigned short hi = f2bf(v);
    ATh[idx] = hi;
    ATl[idx] = f2bf(v - bf2f(hi));
  } else {
    int idx = (blk - NODES / 4 - (CAT_ * 128) / 256) * 256 + threadIdx.x;
    if (idx < 384 * 128) {
      int c = idx >> 7, k = idx & 127;
      float v = Wi[(size_t)k * 384 + c];
      unsigned short hi = f2bf(v);
      WiTh[idx] = hi; WiTl[idx] = f2bf(v - bf2f(hi));
    } else {
      int i = idx - 384 * 128;
      int c = i >> 7, k = i & 127;
      float v = Wh[(size_t)k * 384 + c];
      unsigned short hi = f2bf(v);
      WhTh[i] = hi; WhTl[i] = f2bf(v - bf2f(hi));
    }
  }
}

// ---------------- pack: Gb = bf16(g), Eb = u8(e)  (once) ----------------
__global__ __launch_bounds__(256) void k_pack(const float* __restrict__ g,
                                              const int* __restrict__ e,
                                              unsigned short* __restrict__ Gb,
                                              unsigned char* __restrict__ Eb) {
  size_t i8 = ((size_t)blockIdx.x * 256 + threadIdx.x) * 8;
  float4 g0 = *(const float4*)&g[i8];
  float4 g1 = *(const float4*)&g[i8 + 4];
  int4   e0 = *(const int4*)&e[i8];
  int4   e1 = *(const int4*)&e[i8 + 4];
  ushort4 ga, gb;
  ga.x = f2bf(g0.x); ga.y = f2bf(g0.y); ga.z = f2bf(g0.z); ga.w = f2bf(g0.w);
  gb.x = f2bf(g1.x); gb.y = f2bf(g1.y); gb.z = f2bf(g1.z); gb.w = f2bf(g1.w);
  *(ushort4*)&Gb[i8]     = ga;
  *(ushort4*)&Gb[i8 + 4] = gb;
  uint2 ev;
  ev.x = (unsigned)(e0.x & 0xFF) | ((unsigned)(e0.y & 0xFF) << 8) |
         ((unsigned)(e0.z & 0xFF) << 16) | ((unsigned)(e0.w & 0xFF) << 24);
  ev.y = (unsigned)(e1.x & 0xFF) | ((unsigned)(e1.y & 0xFF) << 8) |
         ((unsigned)(e1.z & 0xFF) << 16) | ((unsigned)(e1.w & 0xFF) << 24);
  *(uint2*)&Eb[i8] = ev;
}

// ---------------- McatT[b][l][o][w] via split-precision bf16 MFMA ----------------
__global__ __launch_bounds__(256) void k_gemmT(const unsigned short* __restrict__ X,
                                               const unsigned short* __restrict__ ATh,
                                               const unsigned short* __restrict__ ATl,
                                               unsigned short* __restrict__ McatT) {
  __shared__ __align__(16) unsigned short Ah[64 * 40];
  __shared__ __align__(16) unsigned short Al[64 * 40];
  __shared__ __align__(16) unsigned short Bh[128 * 40];
  __shared__ __align__(16) unsigned short Bl2[128 * 40];
  const int tid = threadIdx.x;
  const int c0 = blockIdx.x * 128;
  const int node0 = blockIdx.y * 64;
  const int b = node0 >> 10;
  const int w0 = node0 & 1023;
  const int wid = tid >> 6, lane = tid & 63;
  const int wr = wid >> 1, wc = wid & 1;
  const int lr = lane & 15, lg = lane >> 4;
  const int ar = tid >> 2, aq = (tid & 3) * 8;
  const int br = tid >> 1, bq = (tid & 1) * 16;
  f32x4 acc[2][4];
  #pragma unroll
  for (int m = 0; m < 2; ++m)
    #pragma unroll
    for (int n = 0; n < 4; ++n) acc[m][n] = {0.f, 0.f, 0.f, 0.f};
  for (int kk = 0; kk < 4; ++kk) {
    const int kb = kk * 32;
    *(uint4*)&Ah[ar * 40 + aq] = *(const uint4*)&X[(size_t)(node0 + ar) * 256 + kb + aq];
    *(uint4*)&Al[ar * 40 + aq] = *(const uint4*)&X[(size_t)(node0 + ar) * 256 + 128 + kb + aq];
    const unsigned short* bh = ATh + (size_t)(c0 + br) * 128 + kb + bq;
    const unsigned short* bl = ATl + (size_t)(c0 + br) * 128 + kb + bq;
    *(uint4*)&Bh[br * 40 + bq]      = *(const uint4*)bh;
    *(uint4*)&Bh[br * 40 + bq + 8]  = *(const uint4*)(bh + 8);
    *(uint4*)&Bl2[br * 40 + bq]     = *(const uint4*)bl;
    *(uint4*)&Bl2[br * 40 + bq + 8] = *(const uint4*)(bl + 8);
    __syncthreads();
    s16x8 ah[2], al[2], bhf[4], blf[4];
    #pragma unroll
    for (int m = 0; m < 2; ++m) {
      int row = (wr * 32 + m * 16 + lr) * 40 + lg * 8;
      ah[m] = *(const s16x8*)&Ah[row];
      al[m] = *(const s16x8*)&Al[row];
    }
    #pragma unroll
    for (int n = 0; n < 4; ++n) {
      int row = (wc * 64 + n * 16 + lr) * 40 + lg * 8;
      bhf[n] = *(const s16x8*)&Bh[row];
      blf[n] = *(const s16x8*)&Bl2[row];
    }
    #pragma unroll
    for (int m = 0; m < 2; ++m)
      #pragma unroll
      for (int n = 0; n < 4; ++n) {
        acc[m][n] = __builtin_amdgcn_mfma_f32_16x16x32_bf16(ah[m], bhf[n], acc[m][n], 0, 0, 0);
        acc[m][n] = __builtin_amdgcn_mfma_f32_16x16x32_bf16(ah[m], blf[n], acc[m][n], 0, 0, 0);
        acc[m][n] = __builtin_amdgcn_mfma_f32_16x16x32_bf16(al[m], bhf[n], acc[m][n], 0, 0, 0);
      }
    __syncthreads();
  }
  #pragma unroll
  for (int m = 0; m < 2; ++m)
    #pragma unroll
    for (int n = 0; n < 4; ++n) {
      int c = c0 + wc * 64 + n * 16 + lr;
      int l = c >> 7, o = c & 127;
      int w = w0 + wr * 32 + m * 16 + lg * 4;
      ushort4 v;
      v.x = f2bf(acc[m][n][0]); v.y = f2bf(acc[m][n][1]);
      v.z = f2bf(acc[m][n][2]); v.w = f2bf(acc[m][n][3]);
      *(ushort4*)&McatT[(((size_t)b * L_ + l) * MSG2 + o) * N_ + w] = v;
    }
}

// ---------------- agg via 5 masked bf16 MFMA GEMMs (r11-verified form) ----------------
// 64v x 64o tile, KSPLIT=4, grid 1024 (4 blocks/CU), XOR-swizzled LDS, XCD grouping.
// Synchronous staging (reg prefetch across barriers spills: r7/r10; LDS dbuf loses
// occupancy: r12; pre-masking trades VALU for 3x traffic: r13; coarse counted-vmcnt
// null: r16). ~40us is this structure's floor; accepted.
__global__ __launch_bounds__(256, 4) void k_agg_mfma(const unsigned short* __restrict__ Gb,
                                                     const unsigned char* __restrict__ Eb,
                                                     const unsigned short* __restrict__ McatT,
                                                     float* __restrict__ aggP) {
  __shared__ __align__(16) unsigned short Gt[64 * 32];      // 4 KB, swizzled
  __shared__ __align__(16) unsigned char  Et[64 * 40];      // 2.5 KB
  __shared__ __align__(16) unsigned short Bl[L_][64 * 32];  // 20 KB, swizzled
  char* GtB = (char*)Gt;
  char* EtB = (char*)Et;
  char* BlB = (char*)Bl;

  const int tid = threadIdx.x;
  const int fid = blockIdx.x;          // 0..1023
  const int xcd = fid & 7;
  const int s   = fid >> 3;
  const int p   = xcd * 4 + (s >> 5);  // (ks,b) pair 0..31
  const int idx = s & 31;
  const int v0  = (idx & 15) * 64;
  const int oh  = idx >> 4;
  const int ks  = p >> 3;
  const int b   = p & 7;

  const int wid  = tid >> 6, lane = tid & 63;
  const int wr   = wid >> 1, wc = wid & 1;
  const int lr   = lane & 15, lg = lane >> 4;

  f32x4 acc[2][2];
  #pragma unroll
  for (int m = 0; m < 2; ++m)
    #pragma unroll
    for (int n = 0; n < 2; ++n) acc[m][n] = {0.f, 0.f, 0.f, 0.f};

  const int ar = tid >> 2, aq = (tid & 3) * 8;
  const int br = tid >> 2, bq = (tid & 3) * 8;
  const size_t garow = ((size_t)b * N_ + v0 + ar) * N_;
  const size_t mrowb = (((size_t)b * L_) * MSG2 + oh * 64 + br) * N_;
  const size_t lstep = (size_t)MSG2 * N_;
  const int ksbase = ks * 256;

  const int gt_w = (ar * 64 + aq * 2) ^ ((ar & 7) << 4);
  const int et_w = ar * 40 + aq;
  const int bl_w = (br * 64 + bq * 2) ^ ((br & 7) << 4);
  const int fsw  = (lr & 7) << 4;

  for (int kk = 0; kk < 8; ++kk) {
    const int kb = ksbase + kk * 32;
    uint4 gv = *(const uint4*)&Gb[garow + kb + aq];
    uint2 ev = *(const uint2*)&Eb[garow + kb + aq];
    uint4 bv[L_];
    #pragma unroll
    for (int l = 0; l < L_; ++l)
      bv[l] = *(const uint4*)(McatT + mrowb + (size_t)l * lstep + kb + bq);
    *(uint4*)(GtB + gt_w) = gv;
    *(uint2*)(EtB + et_w) = ev;
    #pragma unroll
    for (int l = 0; l < L_; ++l)
      *(uint4*)(BlB + l * (64 * 64) + bl_w) = bv[l];
    __syncthreads();

    s16x8 gt[2]; uint2 et[2];
    #pragma unroll
    for (int m = 0; m < 2; ++m) {
      int row = wr * 32 + m * 16 + lr;
      gt[m] = *(const s16x8*)(GtB + ((row * 64 + lg * 16) ^ fsw));
      et[m] = *(const uint2*)(EtB + row * 40 + lg * 8);
    }
    #pragma unroll
    for (int l = 0; l < L_; ++l) {
      s16x8 bfr[2];
      #pragma unroll
      for (int n = 0; n < 2; ++n) {
        int row = wc * 32 + n * 16 + lr;
        bfr[n] = *(const s16x8*)(BlB + l * (64 * 64) + ((row * 64 + lg * 16) ^ fsw));
      }
      #pragma unroll
      for (int m = 0; m < 2; ++m) {
        unsigned int w0e = et[m].x, w1e = et[m].y;
        s16x8 af;
        af[0] = (((w0e      ) & 0xFFu) == (unsigned)l) ? gt[m][0] : (short)0;
        af[1] = (((w0e >>  8) & 0xFFu) == (unsigned)l) ? gt[m][1] : (short)0;
        af[2] = (((w0e >> 16) & 0xFFu) == (unsigned)l) ? gt[m][2] : (short)0;
        af[3] = (((w0e >> 24) & 0xFFu) == (unsigned)l) ? gt[m][3] : (short)0;
        af[4] = (((w1e      ) & 0xFFu) == (unsigned)l) ? gt[m][4] : (short)0;
        af[5] = (((w1e >>  8) & 0xFFu) == (unsigned)l) ? gt[m][5] : (short)0;
        af[6] = (((w1e >> 16) & 0xFFu) == (unsigned)l) ? gt[m][6] : (short)0;
        af[7] = (((w1e >> 24) & 0xFFu) == (unsigned)l) ? gt[m][7] : (short)0;
        #pragma unroll
        for (int n = 0; n < 2; ++n)
          acc[m][n] = __builtin_amdgcn_mfma_f32_16x16x32_bf16(af, bfr[n], acc[m][n], 0, 0, 0);
      }
    }
    __syncthreads();
  }

  float* op = aggP + ((size_t)ks * NODES + (size_t)b * N_ + v0) * MSG2 + oh * 64;
  #pragma unroll
  for (int m = 0; m < 2; ++m)
    #pragma unroll
    for (int n = 0; n < 2; ++n)
      #pragma unroll
      for (int j = 0; j < 4; ++j) {
        int row = wr * 32 + m * 16 + lg * 4 + j;
        int col = wc * 32 + n * 16 + lr;
        op[(size_t)row * MSG2 + col] = acc[m][n][j];
      }
}

// ---------------- gates via split-precision bf16 MFMA, xprep fused into z=0 A-stage ----------------
// z=0: A = hi/lo bf16 of sum of KSPLIT aggP slabs (computed inline); W = WiT.
// z=1: A = Xh (h hi/lo); W = WhT. gates fp32 [node][768], own buffer (reads aggP live).
__global__ __launch_bounds__(256) void k_gates_mfma(const float* __restrict__ aggP,
                                                    const unsigned short* __restrict__ Xh,
                                                    const unsigned short* __restrict__ WiTh,
                                                    const unsigned short* __restrict__ WiTl,
                                                    const unsigned short* __restrict__ WhTh,
                                                    const unsigned short* __restrict__ WhTl,
                                                    float* __restrict__ gates) {
  __shared__ __align__(16) unsigned short Ah[64 * 40];
  __shared__ __align__(16) unsigned short Al[64 * 40];
  __shared__ __align__(16) unsigned short Bh[128 * 40];
  __shared__ __align__(16) unsigned short Bl2[128 * 40];
  const int tid = threadIdx.x;
  const int z = blockIdx.z;
  const unsigned short* WTh = z ? WhTh : WiTh;
  const unsigned short* WTl = z ? WhTl : WiTl;
  const int c0 = blockIdx.x * 128;
  const int node0 = blockIdx.y * 64;
  const int wid = tid >> 6, lane = tid & 63;
  const int wr = wid >> 1, wc = wid & 1;
  const int lr = lane & 15, lg = lane >> 4;
  const int ar = tid >> 2, aq = (tid & 3) * 8;
  const int br = tid >> 1, bq = (tid & 1) * 16;
  const size_t slab = (size_t)NODES * MSG2;
  f32x4 acc[2][4];
  #pragma unroll
  for (int m = 0; m < 2; ++m)
    #pragma unroll
    for (int n = 0; n < 4; ++n) acc[m][n] = {0.f, 0.f, 0.f, 0.f};
  for (int kk = 0; kk < 4; ++kk) {
    const int kb = kk * 32;
    if (z == 0) {
      // fused xprep: sum KSPLIT slabs (same order as old k_xprep -> identical fp32)
      const float* ap = aggP + (size_t)(node0 + ar) * MSG2 + kb + aq;
      float sv[8] = {0.f, 0.f, 0.f, 0.f, 0.f, 0.f, 0.f, 0.f};
      #pragma unroll
      for (int ss = 0; ss < KSPLIT; ++ss) {
        float4 x0 = *(const float4*)(ap + (size_t)ss * slab);
        float4 x1 = *(const float4*)(ap + (size_t)ss * slab + 4);
        sv[0] += x0.x; sv[1] += x0.y; sv[2] += x0.z; sv[3] += x0.w;
        sv[4] += x1.x; sv[5] += x1.y; sv[6] += x1.z; sv[7] += x1.w;
      }
      s16x8 hv, lv;
      #pragma unroll
      for (int j = 0; j < 8; ++j) {
        unsigned short hi = f2bf(sv[j]);
        hv[j] = (short)hi;
        lv[j] = (short)f2bf(sv[j] - bf2f(hi));
      }
      *(s16x8*)&Ah[ar * 40 + aq] = hv;
      *(s16x8*)&Al[ar * 40 + aq] = lv;
    } else {
      *(uint4*)&Ah[ar * 40 + aq] = *(const uint4*)&Xh[(size_t)(node0 + ar) * 256 + kb + aq];
      *(uint4*)&Al[ar * 40 + aq] = *(const uint4*)&Xh[(size_t)(node0 + ar) * 256 + 128 + kb + aq];
    }
    const unsigned short* bh = WTh + (size_t)(c0 + br) * 128 + kb + bq;
    const unsigned short* bl = WTl + (size_t)(c0 + br) * 128 + kb + bq;
    *(uint4*)&Bh[br * 40 + bq]      = *(const uint4*)bh;
    *(uint4*)&Bh[br * 40 + bq + 8]  = *(const uint4*)(bh + 8);
    *(uint4*)&Bl2[br * 40 + bq]     = *(const uint4*)bl;
    *(uint4*)&Bl2[br * 40 + bq + 8] = *(const uint4*)(bl + 8);
    __syncthreads();
    s16x8 ah[2], al[2], bhf[4], blf[4];
    #pragma unroll
    for (int m = 0; m < 2; ++m) {
      int row = (wr * 32 + m * 16 + lr) * 40 + lg * 8;
      ah[m] = *(const s16x8*)&Ah[row];
      al[m] = *(const s16x8*)&Al[row];
    }
    #pragma unroll
    for (int n = 0; n < 4; ++n) {
      int row = (wc * 64 + n * 16 + lr) * 40 + lg * 8;
      bhf[n] = *(const s16x8*)&Bh[row];
      blf[n] = *(const s16x8*)&Bl2[row];
    }
    #pragma unroll
    for (int m = 0; m < 2; ++m)
      #pragma unroll
      for (int n = 0; n < 4; ++n) {
        acc[m][n] = __builtin_amdgcn_mfma_f32_16x16x32_bf16(ah[m], bhf[n], acc[m][n], 0, 0, 0);
        acc[m][n] = __builtin_amdgcn_mfma_f32_16x16x32_bf16(ah[m], blf[n], acc[m][n], 0, 0, 0);
        acc[m][n] = __builtin_amdgcn_mfma_f32_16x16x32_bf16(al[m], bhf[n], acc[m][n], 0, 0, 0);
      }
    __syncthreads();
  }
  #pragma unroll
  for (int m = 0; m < 2; ++m)
    #pragma unroll
    for (int n = 0; n < 4; ++n) {
      int c = c0 + wc * 64 + n * 16 + lr;
      int row = node0 + wr * 32 + m * 16 + lg * 4;
      #pragma unroll
      for (int j = 0; j < 4; ++j)
        gates[(size_t)(row + j) * 768 + z * 384 + c] = acc[m][n][j];
    }
}

// ---------------- GRU elementwise (+ optional X hi/lo write) ----------------
__global__ __launch_bounds__(256) void k_gru_elt(const float* __restrict__ gates,
                                                 const float* __restrict__ bi,
                                                 const float* __restrict__ bh,
                                                 const float* __restrict__ maskA,
                                                 float* __restrict__ h,
                                                 unsigned short* __restrict__ X,
                                                 int writeX) {
  const int t = threadIdx.x;
  const int node = blockIdx.x * 8 + (t >> 5);
  const int j4 = (t & 31) * 4;
  const size_t gb = (size_t)node * 768;
  float4 gir = *(const float4*)&gates[gb + j4];
  float4 giz = *(const float4*)&gates[gb + 128 + j4];
  float4 gin = *(const float4*)&gates[gb + 256 + j4];
  float4 ghr = *(const float4*)&gates[gb + 384 + j4];
  float4 ghz = *(const float4*)&gates[gb + 512 + j4];
  float4 ghn = *(const float4*)&gates[gb + 640 + j4];
  float4 bir = *(const float4*)&bi[j4];
  float4 biz = *(const float4*)&bi[128 + j4];
  float4 bin = *(const float4*)&bi[256 + j4];
  float4 bhr = *(const float4*)&bh[j4];
  float4 bhz = *(const float4*)&bh[128 + j4];
  float4 bhn = *(const float4*)&bh[256 + j4];
  float4 hv = *(const float4*)&h[(size_t)node * 128 + j4];
  float m = maskA[node];
  float4 ho;
  {
    float r = sigmoidf_(gir.x + bir.x + ghr.x + bhr.x);
    float z = sigmoidf_(giz.x + biz.x + ghz.x + bhz.x);
    float nn = tanhf(gin.x + bin.x + r * (ghn.x + bhn.x));
    ho.x = ((1.f - z) * nn + z * hv.x) * m;
  }
  {
    float r = sigmoidf_(gir.y + bir.y + ghr.y + bhr.y);
    float z = sigmoidf_(giz.y + biz.y + ghz.y + bhz.y);
    float nn = tanhf(gin.y + bin.y + r * (ghn.y + bhn.y));
    ho.y = ((1.f - z) * nn + z * hv.y) * m;
  }
  {
    float r = sigmoidf_(gir.z + bir.z + ghr.z + bhr.z);
    float z = sigmoidf_(giz.z + biz.z + ghz.z + bhz.z);
    float nn = tanhf(gin.z + bin.z + r * (ghn.z + bhn.z));
    ho.z = ((1.f - z) * nn + z * hv.z) * m;
  }
  {
    float r = sigmoidf_(gir.w + bir.w + ghr.w + bhr.w);
    float z = sigmoidf_(giz.w + biz.w + ghz.w + bhz.w);
    float nn = tanhf(gin.w + bin.w + r * (ghn.w + bhn.w));
    ho.w = ((1.f - z) * nn + z * hv.w) * m;
  }
  *(float4*)&h[(size_t)node * 128 + j4] = ho;
  if (writeX) {
    ushort4 hi, lo;
    hi.x = f2bf(ho.x); lo.x = f2bf(ho.x - bf2f(hi.x));
    hi.y = f2bf(ho.y); lo.y = f2bf(ho.y - bf2f(hi.y));
    hi.z = f2bf(ho.z); lo.z = f2bf(ho.z - bf2f(hi.z));
    hi.w = f2bf(ho.w); lo.w = f2bf(ho.w - bf2f(hi.w));
    *(ushort4*)&X[(size_t)node * 256 + j4]       = hi;
    *(ushort4*)&X[(size_t)node * 256 + 128 + j4] = lo;
  }
}

// ---------------- readout stage 1: PT[c][node] = ([hT,h0] @ Wcat)[node][c] ----------------
__global__ __launch_bounds__(256) void k_readP(const float* __restrict__ h,
                                               const float* __restrict__ h0,
                                               const float* __restrict__ Wg,
                                               const float* __restrict__ Wo,
                                               float* __restrict__ PT) {
  __shared__ float Xt[64][65];
  __shared__ float Wt[64][25];
  const int tid = threadIdx.x;
  const int node0 = blockIdx.x * 64;
  const int row = tid >> 2;
  const int cg  = tid & 3;
  float acc[6] = {0.f, 0.f, 0.f, 0.f, 0.f, 0.f};
  const int sr = tid >> 2;
  const int sk = (tid & 3) * 16;
  #pragma unroll
  for (int kb = 0; kb < 4; ++kb) {
    const float* src = (kb < 2 ? h : h0) + (size_t)(node0 + sr) * 128 + (kb & 1) * 64 + sk;
    #pragma unroll
    for (int q = 0; q < 4; ++q)
      *(float4*)&Xt[sr][sk + q * 4] = *(const float4*)(src + q * 4);
    #pragma unroll
    for (int j = 0; j < 6; ++j) {
      int idx = tid * 6 + j;
      int rk = idx / 24;
      int c24 = idx - rk * 24;
      int gk = kb * 64 + rk;
      float wv;
      if (c24 < 12) wv = Wg[(size_t)gk * TGT_ + c24];
      else          wv = (gk < 128) ? Wo[(size_t)gk * TGT_ + (c24 - 12)] : 0.f;
      Wt[rk][c24] = wv;
    }
    __syncthreads();
    #pragma unroll 8
    for (int k = 0; k < 64; ++k) {
      float x = Xt[row][k];
      #pragma unroll
      for (int j = 0; j < 6; ++j)
        acc[j] += x * Wt[k][cg * 6 + j];
    }
    __syncthreads();
  }
  #pragma unroll
  for (int j = 0; j < 6; ++j)
    PT[(size_t)(cg * 6 + j) * NODES + node0 + row] = acc[j];
}

// ---------------- readout stage 2 ----------------
__global__ __launch_bounds__(256) void k_readR(const float* __restrict__ PT,
                                               const float* __restrict__ maskR,
                                               const float* __restrict__ bg,
                                               const float* __restrict__ bo,
                                               float* __restrict__ out) {
  __shared__ float red[256];
  const int tid = threadIdx.x;
  const int b = blockIdx.x / TGT_;
  const int t = blockIdx.x - b * TGT_;
  const float bgt = bg[t], bot = bo[t];
  float s = 0.f;
  #pragma unroll
  for (int i = 0; i < 4; ++i) {
    int node = b * N_ + i * 256 + tid;
    float p1 = PT[(size_t)t * NODES + node] + bgt;
    float p2 = PT[(size_t)(12 + t) * NODES + node] + bot;
    s += sigmoidf_(p1) * p2 * maskR[node];
  }
  red[tid] = s;
  __syncthreads();
  #pragma unroll
  for (int off = 128; off > 0; off >>= 1) {
    if (tid < off) red[tid] += red[tid + off];
    __syncthreads();
  }
  if (tid == 0) out[b * TGT_ + t] = red[0];
}

extern "C" void kernel_launch(void* const* d_in, const int* in_sizes, int n_in,
                              void* d_out, int out_size, void* d_ws, size_t ws_size,
                              hipStream_t stream) {
  (void)in_sizes; (void)n_in; (void)out_size; (void)ws_size;
  const float* g    = (const float*)d_in[0];
  const float* h_in = (const float*)d_in[1];
  const int*   e    = (const int*)d_in[2];
  const float* A    = (const float*)d_in[3];
  const float* Wi   = (const float*)d_in[4];
  const float* Wh   = (const float*)d_in[5];
  const float* bi   = (const float*)d_in[6];
  const float* bh   = (const float*)d_in[7];
  const float* Wg   = (const float*)d_in[8];
  const float* bg   = (const float*)d_in[9];
  const float* Wo   = (const float*)d_in[10];
  const float* bo   = (const float*)d_in[11];
  float* out = (float*)d_out;
  float* ws  = (float*)d_ws;

  // workspace layout (~92 MB):
  float* h     = ws;                                   // 1,048,576 f
  float* h0    = h + (size_t)NODES * H_;               // 1,048,576 f
  float* maskA = h0 + (size_t)NODES * H_;              // 8192 f
  float* maskR = maskA + NODES;                        // 8192 f
  float* PT    = maskR + NODES;                        // 196,608 f (readout scratch)
  unsigned short* X    = (unsigned short*)(PT + 24 * NODES);  // 2,097,152 us (h hi|lo)
  unsigned short* ATh  = X + (size_t)NODES * 256;      // 81,920 us
  unsigned short* ATl  = ATh + CAT_ * 128;             // 81,920 us
  unsigned short* WiTh = ATl + CAT_ * 128;             // 49,152 us
  unsigned short* WiTl = WiTh + 384 * 128;             // 49,152 us
  unsigned short* WhTh = WiTl + 384 * 128;             // 49,152 us
  unsigned short* WhTl = WhTh + 384 * 128;             // 49,152 us
  unsigned short* Gb   = WhTl + 384 * 128;             // 8,388,608 us (16.8 MB)
  unsigned char*  Eb   = (unsigned char*)(Gb + (size_t)NODES * N_);   // 8,388,608 u8
  float* aggP = (float*)(Eb + (size_t)NODES * N_);     // KSPLIT * 1,048,576 f (16.8 MB)
  unsigned short* McatT = (unsigned short*)(aggP + (size_t)KSPLIT * NODES * MSG2); // 10.5 MB
  // gates has its OWN region now: k_gates reads aggP while writing gates (fused xprep).
  float* gates = (float*)(McatT + (size_t)B_ * L_ * MSG2 * N_);       // 6,291,456 f (25.2 MB)

  k_prep<<<NODES / 4 + (CAT_ * 128) / 256 + (2 * 384 * 128) / 256, 256, 0, stream>>>(
      h_in, A, Wi, Wh, h, h0, X, maskA, maskR, ATh, ATl, WiTh, WiTl, WhTh, WhTl);
  k_pack<<<(NODES * N_ / 8) / 256, 256, 0, stream>>>(g, e, Gb, Eb);
  for (int layer = 0; layer < NLAYERS_; ++layer) {
    k_gemmT<<<dim3(CAT_ / 128, NODES / 64), 256, 0, stream>>>(X, ATh, ATl, McatT);
    k_agg_mfma<<<(N_ / 64) * 2 * KSPLIT * B_, 256, 0, stream>>>(Gb, Eb, McatT, aggP);
    k_gates_mfma<<<dim3(384 / 128, NODES / 64, 2), 256, 0, stream>>>(aggP, X, WiTh, WiTl, WhTh, WhTl, gates);
    k_gru_elt<<<NODES / 8, 256, 0, stream>>>(gates, bi, bh, maskA, h, X,
                                             (layer < NLAYERS_ - 1) ? 1 : 0);
  }
  k_readP<<<NODES / 64, 256, 0, stream>>>(h, h0, Wg, Wo, PT);
  k_readR<<<B_ * TGT_, 256, 0, stream>>>(PT, maskR, bg, bo, out);
}

// Round 18
// 219.840 us; speedup vs baseline: 1.1724x; 1.0042x over previous
//
#include <hip/hip_runtime.h>

#define B_      8
#define N_      1024
#define DIN_    64
#define H_      128
#define MSG2    128
#define L_      5
#define TGT_    12
#define NLAYERS_ 3
#define CAT_    640          // L_ * MSG2
#define NODES   (B_ * N_)    // 8192
#define KSPLIT  4

typedef __attribute__((ext_vector_type(8))) short s16x8;
typedef __attribute__((ext_vector_type(4))) float f32x4;

__device__ __forceinline__ float sigmoidf_(float x) { return 1.f / (1.f + __expf(-x)); }

__device__ __forceinline__ unsigned short f2bf(float x) {
  unsigned int u = __float_as_uint(x);
  u += 0x7FFFu + ((u >> 16) & 1u);      // round-to-nearest-even
  return (unsigned short)(u >> 16);
}
__device__ __forceinline__ float bf2f(unsigned short u) {
  return __uint_as_float(((unsigned int)u) << 16);
}

// ---------------- merged prep: init | aprep | wprep ----------------
__global__ __launch_bounds__(256) void k_prep(const float* __restrict__ h_in,
                                              const float* __restrict__ A,
                                              const float* __restrict__ Wi,
                                              const float* __restrict__ Wh,
                                              float* __restrict__ h,
                                              float* __restrict__ h0,
                                              unsigned short* __restrict__ X,
                                              float* __restrict__ maskA,
                                              float* __restrict__ maskR,
                                              unsigned short* __restrict__ ATh,
                                              unsigned short* __restrict__ ATl,
                                              unsigned short* __restrict__ WiTh,
                                              unsigned short* __restrict__ WiTl,
                                              unsigned short* __restrict__ WhTh,
                                              unsigned short* __restrict__ WhTl) {
  const int blk = blockIdx.x;
  if (blk < NODES / 4) {
    int node = blk * 4 + (threadIdx.x >> 6);
    int lane = threadIdx.x & 63;
    float v = h_in[(size_t)node * DIN_ + lane];
    size_t base = (size_t)node * H_;
    h[base + lane] = v;   h[base + 64 + lane] = 0.f;
    h0[base + lane] = v;  h0[base + 64 + lane] = 0.f;
    unsigned short hi = f2bf(v);
    unsigned short lo = f2bf(v - bf2f(hi));
    size_t xb = (size_t)node * 256;
    X[xb + lane] = hi;        X[xb + 64 + lane] = 0;
    X[xb + 128 + lane] = lo;  X[xb + 192 + lane] = 0;
    float sa = fabsf(v), ss = v;
    for (int off = 32; off > 0; off >>= 1) {
      sa += __shfl_down(sa, off);
      ss += __shfl_down(ss, off);
    }
    if (lane == 0) {
      maskA[node] = (sa > 0.f) ? 1.f : 0.f;
      maskR[node] = (ss > 0.f) ? 1.f : 0.f;
    }
  } else if (blk < NODES / 4 + (CAT_ * 128) / 256) {
    int idx = (blk - NODES / 4) * 256 + threadIdx.x;
    int c = idx >> 7, d = idx & 127;
    int l = c >> 7, o = c & 127;
    float v = A[((size_t)l * 128 + d) * 128 + o];
    unsigned short hi = f2bf(v);
    ATh[idx] = hi;
    ATl[idx] = f2bf(v - bf2f(hi));
  } else {
    int idx = (blk - NODES / 4 - (CAT_ * 128) / 256) * 256 + threadIdx.x;
    if (idx < 384 * 128) {
      int c = idx >> 7, k = idx & 127;
      float v = Wi[(size_t)k * 384 + c];
      unsigned short hi = f2bf(v);
      WiTh[idx] = hi; WiTl[idx] = f2bf(v - bf2f(hi));
    } else {
      int i = idx - 384 * 128;
      int c = i >> 7, k = i & 127;
      float v = Wh[(size_t)k * 384 + c];
      unsigned short hi = f2bf(v);
      WhTh[i] = hi; WhTl[i] = f2bf(v - bf2f(hi));
    }
  }
}

// ---------------- pack: Gb = bf16(g), Eb = u8(e)  (once) ----------------
__global__ __launch_bounds__(256) void k_pack(const float* __restrict__ g,
                                              const int* __restrict__ e,
                                              unsigned short* __restrict__ Gb,
                                              unsigned char* __restrict__ Eb) {
  size_t i8 = ((size_t)blockIdx.x * 256 + threadIdx.x) * 8;
  float4 g0 = *(const float4*)&g[i8];
  float4 g1 = *(const float4*)&g[i8 + 4];
  int4   e0 = *(const int4*)&e[i8];
  int4   e1 = *(const int4*)&e[i8 + 4];
  ushort4 ga, gb;
  ga.x = f2bf(g0.x); ga.y = f2bf(g0.y); ga.z = f2bf(g0.z); ga.w = f2bf(g0.w);
  gb.x = f2bf(g1.x); gb.y = f2bf(g1.y); gb.z = f2bf(g1.z); gb.w = f2bf(g1.w);
  *(ushort4*)&Gb[i8]     = ga;
  *(ushort4*)&Gb[i8 + 4] = gb;
  uint2 ev;
  ev.x = (unsigned)(e0.x & 0xFF) | ((unsigned)(e0.y & 0xFF) << 8) |
         ((unsigned)(e0.z & 0xFF) << 16) | ((unsigned)(e0.w & 0xFF) << 24);
  ev.y = (unsigned)(e1.x & 0xFF) | ((unsigned)(e1.y & 0xFF) << 8) |
         ((unsigned)(e1.z & 0xFF) << 16) | ((unsigned)(e1.w & 0xFF) << 24);
  *(uint2*)&Eb[i8] = ev;
}

// ---------------- McatT[b][l][o][w] via split-precision bf16 MFMA ----------------
__global__ __launch_bounds__(256) void k_gemmT(const unsigned short* __restrict__ X,
                                               const unsigned short* __restrict__ ATh,
                                               const unsigned short* __restrict__ ATl,
                                               unsigned short* __restrict__ McatT) {
  __shared__ __align__(16) unsigned short Ah[64 * 40];
  __shared__ __align__(16) unsigned short Al[64 * 40];
  __shared__ __align__(16) unsigned short Bh[128 * 40];
  __shared__ __align__(16) unsigned short Bl2[128 * 40];
  const int tid = threadIdx.x;
  const int c0 = blockIdx.x * 128;
  const int node0 = blockIdx.y * 64;
  const int b = node0 >> 10;
  const int w0 = node0 & 1023;
  const int wid = tid >> 6, lane = tid & 63;
  const int wr = wid >> 1, wc = wid & 1;
  const int lr = lane & 15, lg = lane >> 4;
  const int ar = tid >> 2, aq = (tid & 3) * 8;
  const int br = tid >> 1, bq = (tid & 1) * 16;
  f32x4 acc[2][4];
  #pragma unroll
  for (int m = 0; m < 2; ++m)
    #pragma unroll
    for (int n = 0; n < 4; ++n) acc[m][n] = {0.f, 0.f, 0.f, 0.f};
  for (int kk = 0; kk < 4; ++kk) {
    const int kb = kk * 32;
    *(uint4*)&Ah[ar * 40 + aq] = *(const uint4*)&X[(size_t)(node0 + ar) * 256 + kb + aq];
    *(uint4*)&Al[ar * 40 + aq] = *(const uint4*)&X[(size_t)(node0 + ar) * 256 + 128 + kb + aq];
    const unsigned short* bh = ATh + (size_t)(c0 + br) * 128 + kb + bq;
    const unsigned short* bl = ATl + (size_t)(c0 + br) * 128 + kb + bq;
    *(uint4*)&Bh[br * 40 + bq]      = *(const uint4*)bh;
    *(uint4*)&Bh[br * 40 + bq + 8]  = *(const uint4*)(bh + 8);
    *(uint4*)&Bl2[br * 40 + bq]     = *(const uint4*)bl;
    *(uint4*)&Bl2[br * 40 + bq + 8] = *(const uint4*)(bl + 8);
    __syncthreads();
    s16x8 ah[2], al[2], bhf[4], blf[4];
    #pragma unroll
    for (int m = 0; m < 2; ++m) {
      int row = (wr * 32 + m * 16 + lr) * 40 + lg * 8;
      ah[m] = *(const s16x8*)&Ah[row];
      al[m] = *(const s16x8*)&Al[row];
    }
    #pragma unroll
    for (int n = 0; n < 4; ++n) {
      int row = (wc * 64 + n * 16 + lr) * 40 + lg * 8;
      bhf[n] = *(const s16x8*)&Bh[row];
      blf[n] = *(const s16x8*)&Bl2[row];
    }
    #pragma unroll
    for (int m = 0; m < 2; ++m)
      #pragma unroll
      for (int n = 0; n < 4; ++n) {
        acc[m][n] = __builtin_amdgcn_mfma_f32_16x16x32_bf16(ah[m], bhf[n], acc[m][n], 0, 0, 0);
        acc[m][n] = __builtin_amdgcn_mfma_f32_16x16x32_bf16(ah[m], blf[n], acc[m][n], 0, 0, 0);
        acc[m][n] = __builtin_amdgcn_mfma_f32_16x16x32_bf16(al[m], bhf[n], acc[m][n], 0, 0, 0);
      }
    __syncthreads();
  }
  #pragma unroll
  for (int m = 0; m < 2; ++m)
    #pragma unroll
    for (int n = 0; n < 4; ++n) {
      int c = c0 + wc * 64 + n * 16 + lr;
      int l = c >> 7, o = c & 127;
      int w = w0 + wr * 32 + m * 16 + lg * 4;
      ushort4 v;
      v.x = f2bf(acc[m][n][0]); v.y = f2bf(acc[m][n][1]);
      v.z = f2bf(acc[m][n][2]); v.w = f2bf(acc[m][n][3]);
      *(ushort4*)&McatT[(((size_t)b * L_ + l) * MSG2 + o) * N_ + w] = v;
    }
}

// ---------------- agg via 5 per-label bf16 MFMA GEMMs, STAGING-SIDE masking ----------------
// 64v x 64o tile, KSPLIT=4, grid 1024 (4 blocks/CU, LDS exactly 40KB), XOR swizzle,
// XCD grouping. r18 change: masked A-tiles built ONCE at staging (80 VALU/lane)
// instead of per-compute-wave (240 VALU/lane x all waves) — 3x less mask VALU,
// compute loop is pure ds_read+MFMA. Same mask/bf16/MFMA order => bit-identical.
__global__ __launch_bounds__(256, 4) void k_agg_mfma(const unsigned short* __restrict__ Gb,
                                                     const unsigned char* __restrict__ Eb,
                                                     const unsigned short* __restrict__ McatT,
                                                     float* __restrict__ aggP) {
  __shared__ __align__(16) unsigned short Gm[L_][64 * 32];  // 20 KB, pre-masked, swizzled
  __shared__ __align__(16) unsigned short Bl[L_][64 * 32];  // 20 KB, swizzled
  char* GmB = (char*)Gm;   // label stride 4096 B
  char* BlB = (char*)Bl;

  const int tid = threadIdx.x;
  const int fid = blockIdx.x;          // 0..1023
  const int xcd = fid & 7;
  const int s   = fid >> 3;
  const int p   = xcd * 4 + (s >> 5);  // (ks,b) pair 0..31
  const int idx = s & 31;
  const int v0  = (idx & 15) * 64;
  const int oh  = idx >> 4;
  const int ks  = p >> 3;
  const int b   = p & 7;

  const int wid  = tid >> 6, lane = tid & 63;
  const int wr   = wid >> 1, wc = wid & 1;    // wave tile 32v x 32o
  const int lr   = lane & 15, lg = lane >> 4;

  f32x4 acc[2][2];
  #pragma unroll
  for (int m = 0; m < 2; ++m)
    #pragma unroll
    for (int n = 0; n < 2; ++n) acc[m][n] = {0.f, 0.f, 0.f, 0.f};

  const int ar = tid >> 2, aq = (tid & 3) * 8;
  const int br = tid >> 2, bq = (tid & 3) * 8;
  const size_t garow = ((size_t)b * N_ + v0 + ar) * N_;
  const size_t mrowb = (((size_t)b * L_) * MSG2 + oh * 64 + br) * N_;
  const size_t lstep = (size_t)MSG2 * N_;
  const int ksbase = ks * 256;

  const int gt_w = (ar * 64 + aq * 2) ^ ((ar & 7) << 4);
  const int bl_w = (br * 64 + bq * 2) ^ ((br & 7) << 4);
  const int fsw  = (lr & 7) << 4;

  for (int kk = 0; kk < 8; ++kk) {
    const int kb = ksbase + kk * 32;
    s16x8 gs = *(const s16x8*)&Gb[garow + kb + aq];
    uint2 ev = *(const uint2*)&Eb[garow + kb + aq];
    uint4 bv[L_];
    #pragma unroll
    for (int l = 0; l < L_; ++l)
      bv[l] = *(const uint4*)(McatT + mrowb + (size_t)l * lstep + kb + bq);
    // staging-side masking: 5 masked copies of this thread's 8 g-elements
    {
      unsigned int w0e = ev.x, w1e = ev.y;
      #pragma unroll
      for (int l = 0; l < L_; ++l) {
        s16x8 mg;
        mg[0] = (((w0e      ) & 0xFFu) == (unsigned)l) ? gs[0] : (short)0;
        mg[1] = (((w0e >>  8) & 0xFFu) == (unsigned)l) ? gs[1] : (short)0;
        mg[2] = (((w0e >> 16) & 0xFFu) == (unsigned)l) ? gs[2] : (short)0;
        mg[3] = (((w0e >> 24) & 0xFFu) == (unsigned)l) ? gs[3] : (short)0;
        mg[4] = (((w1e      ) & 0xFFu) == (unsigned)l) ? gs[4] : (short)0;
        mg[5] = (((w1e >>  8) & 0xFFu) == (unsigned)l) ? gs[5] : (short)0;
        mg[6] = (((w1e >> 16) & 0xFFu) == (unsigned)l) ? gs[6] : (short)0;
        mg[7] = (((w1e >> 24) & 0xFFu) == (unsigned)l) ? gs[7] : (short)0;
        *(s16x8*)(GmB + l * 4096 + gt_w) = mg;
      }
    }
    #pragma unroll
    for (int l = 0; l < L_; ++l)
      *(uint4*)(BlB + l * (64 * 64) + bl_w) = bv[l];
    __syncthreads();

    #pragma unroll
    for (int l = 0; l < L_; ++l) {
      s16x8 af[2], bfr[2];
      #pragma unroll
      for (int m = 0; m < 2; ++m) {
        int row = wr * 32 + m * 16 + lr;
        af[m] = *(const s16x8*)(GmB + l * 4096 + ((row * 64 + lg * 16) ^ fsw));
      }
      #pragma unroll
      for (int n = 0; n < 2; ++n) {
        int row = wc * 32 + n * 16 + lr;
        bfr[n] = *(const s16x8*)(BlB + l * (64 * 64) + ((row * 64 + lg * 16) ^ fsw));
      }
      #pragma unroll
      for (int m = 0; m < 2; ++m)
        #pragma unroll
        for (int n = 0; n < 2; ++n)
          acc[m][n] = __builtin_amdgcn_mfma_f32_16x16x32_bf16(af[m], bfr[n], acc[m][n], 0, 0, 0);
    }
    __syncthreads();
  }

  float* op = aggP + ((size_t)ks * NODES + (size_t)b * N_ + v0) * MSG2 + oh * 64;
  #pragma unroll
  for (int m = 0; m < 2; ++m)
    #pragma unroll
    for (int n = 0; n < 2; ++n)
      #pragma unroll
      for (int j = 0; j < 4; ++j) {
        int row = wr * 32 + m * 16 + lg * 4 + j;
        int col = wc * 32 + n * 16 + lr;
        op[(size_t)row * MSG2 + col] = acc[m][n][j];
      }
}

// ---------------- gates via split-precision bf16 MFMA, xprep fused into z=0 A-stage ----------------
__global__ __launch_bounds__(256) void k_gates_mfma(const float* __restrict__ aggP,
                                                    const unsigned short* __restrict__ Xh,
                                                    const unsigned short* __restrict__ WiTh,
                                                    const unsigned short* __restrict__ WiTl,
                                                    const unsigned short* __restrict__ WhTh,
                                                    const unsigned short* __restrict__ WhTl,
                                                    float* __restrict__ gates) {
  __shared__ __align__(16) unsigned short Ah[64 * 40];
  __shared__ __align__(16) unsigned short Al[64 * 40];
  __shared__ __align__(16) unsigned short Bh[128 * 40];
  __shared__ __align__(16) unsigned short Bl2[128 * 40];
  const int tid = threadIdx.x;
  const int z = blockIdx.z;
  const unsigned short* WTh = z ? WhTh : WiTh;
  const unsigned short* WTl = z ? WhTl : WiTl;
  const int c0 = blockIdx.x * 128;
  const int node0 = blockIdx.y * 64;
  const int wid = tid >> 6, lane = tid & 63;
  const int wr = wid >> 1, wc = wid & 1;
  const int lr = lane & 15, lg = lane >> 4;
  const int ar = tid >> 2, aq = (tid & 3) * 8;
  const int br = tid >> 1, bq = (tid & 1) * 16;
  const size_t slab = (size_t)NODES * MSG2;
  f32x4 acc[2][4];
  #pragma unroll
  for (int m = 0; m < 2; ++m)
    #pragma unroll
    for (int n = 0; n < 4; ++n) acc[m][n] = {0.f, 0.f, 0.f, 0.f};
  for (int kk = 0; kk < 4; ++kk) {
    const int kb = kk * 32;
    if (z == 0) {
      const float* ap = aggP + (size_t)(node0 + ar) * MSG2 + kb + aq;
      float sv[8] = {0.f, 0.f, 0.f, 0.f, 0.f, 0.f, 0.f, 0.f};
      #pragma unroll
      for (int ss = 0; ss < KSPLIT; ++ss) {
        float4 x0 = *(const float4*)(ap + (size_t)ss * slab);
        float4 x1 = *(const float4*)(ap + (size_t)ss * slab + 4);
        sv[0] += x0.x; sv[1] += x0.y; sv[2] += x0.z; sv[3] += x0.w;
        sv[4] += x1.x; sv[5] += x1.y; sv[6] += x1.z; sv[7] += x1.w;
      }
      s16x8 hv, lv;
      #pragma unroll
      for (int j = 0; j < 8; ++j) {
        unsigned short hi = f2bf(sv[j]);
        hv[j] = (short)hi;
        lv[j] = (short)f2bf(sv[j] - bf2f(hi));
      }
      *(s16x8*)&Ah[ar * 40 + aq] = hv;
      *(s16x8*)&Al[ar * 40 + aq] = lv;
    } else {
      *(uint4*)&Ah[ar * 40 + aq] = *(const uint4*)&Xh[(size_t)(node0 + ar) * 256 + kb + aq];
      *(uint4*)&Al[ar * 40 + aq] = *(const uint4*)&Xh[(size_t)(node0 + ar) * 256 + 128 + kb + aq];
    }
    const unsigned short* bh = WTh + (size_t)(c0 + br) * 128 + kb + bq;
    const unsigned short* bl = WTl + (size_t)(c0 + br) * 128 + kb + bq;
    *(uint4*)&Bh[br * 40 + bq]      = *(const uint4*)bh;
    *(uint4*)&Bh[br * 40 + bq + 8]  = *(const uint4*)(bh + 8);
    *(uint4*)&Bl2[br * 40 + bq]     = *(const uint4*)bl;
    *(uint4*)&Bl2[br * 40 + bq + 8] = *(const uint4*)(bl + 8);
    __syncthreads();
    s16x8 ah[2], al[2], bhf[4], blf[4];
    #pragma unroll
    for (int m = 0; m < 2; ++m) {
      int row = (wr * 32 + m * 16 + lr) * 40 + lg * 8;
      ah[m] = *(const s16x8*)&Ah[row];
      al[m] = *(const s16x8*)&Al[row];
    }
    #pragma unroll
    for (int n = 0; n < 4; ++n) {
      int row = (wc * 64 + n * 16 + lr) * 40 + lg * 8;
      bhf[n] = *(const s16x8*)&Bh[row];
      blf[n] = *(const s16x8*)&Bl2[row];
    }
    #pragma unroll
    for (int m = 0; m < 2; ++m)
      #pragma unroll
      for (int n = 0; n < 4; ++n) {
        acc[m][n] = __builtin_amdgcn_mfma_f32_16x16x32_bf16(ah[m], bhf[n], acc[m][n], 0, 0, 0);
        acc[m][n] = __builtin_amdgcn_mfma_f32_16x16x32_bf16(ah[m], blf[n], acc[m][n], 0, 0, 0);
        acc[m][n] = __builtin_amdgcn_mfma_f32_16x16x32_bf16(al[m], bhf[n], acc[m][n], 0, 0, 0);
      }
    __syncthreads();
  }
  #pragma unroll
  for (int m = 0; m < 2; ++m)
    #pragma unroll
    for (int n = 0; n < 4; ++n) {
      int c = c0 + wc * 64 + n * 16 + lr;
      int row = node0 + wr * 32 + m * 16 + lg * 4;
      #pragma unroll
      for (int j = 0; j < 4; ++j)
        gates[(size_t)(row + j) * 768 + z * 384 + c] = acc[m][n][j];
    }
}

// ---------------- GRU elementwise (+ optional X hi/lo write) ----------------
__global__ __launch_bounds__(256) void k_gru_elt(const float* __restrict__ gates,
                                                 const float* __restrict__ bi,
                                                 const float* __restrict__ bh,
                                                 const float* __restrict__ maskA,
                                                 float* __restrict__ h,
                                                 unsigned short* __restrict__ X,
                                                 int writeX) {
  const int t = threadIdx.x;
  const int node = blockIdx.x * 8 + (t >> 5);
  const int j4 = (t & 31) * 4;
  const size_t gb = (size_t)node * 768;
  float4 gir = *(const float4*)&gates[gb + j4];
  float4 giz = *(const float4*)&gates[gb + 128 + j4];
  float4 gin = *(const float4*)&gates[gb + 256 + j4];
  float4 ghr = *(const float4*)&gates[gb + 384 + j4];
  float4 ghz = *(const float4*)&gates[gb + 512 + j4];
  float4 ghn = *(const float4*)&gates[gb + 640 + j4];
  float4 bir = *(const float4*)&bi[j4];
  float4 biz = *(const float4*)&bi[128 + j4];
  float4 bin = *(const float4*)&bi[256 + j4];
  float4 bhr = *(const float4*)&bh[j4];
  float4 bhz = *(const float4*)&bh[128 + j4];
  float4 bhn = *(const float4*)&bh[256 + j4];
  float4 hv = *(const float4*)&h[(size_t)node * 128 + j4];
  float m = maskA[node];
  float4 ho;
  {
    float r = sigmoidf_(gir.x + bir.x + ghr.x + bhr.x);
    float z = sigmoidf_(giz.x + biz.x + ghz.x + bhz.x);
    float nn = tanhf(gin.x + bin.x + r * (ghn.x + bhn.x));
    ho.x = ((1.f - z) * nn + z * hv.x) * m;
  }
  {
    float r = sigmoidf_(gir.y + bir.y + ghr.y + bhr.y);
    float z = sigmoidf_(giz.y + biz.y + ghz.y + bhz.y);
    float nn = tanhf(gin.y + bin.y + r * (ghn.y + bhn.y));
    ho.y = ((1.f - z) * nn + z * hv.y) * m;
  }
  {
    float r = sigmoidf_(gir.z + bir.z + ghr.z + bhr.z);
    float z = sigmoidf_(giz.z + biz.z + ghz.z + bhz.z);
    float nn = tanhf(gin.z + bin.z + r * (ghn.z + bhn.z));
    ho.z = ((1.f - z) * nn + z * hv.z) * m;
  }
  {
    float r = sigmoidf_(gir.w + bir.w + ghr.w + bhr.w);
    float z = sigmoidf_(giz.w + biz.w + ghz.w + bhz.w);
    float nn = tanhf(gin.w + bin.w + r * (ghn.w + bhn.w));
    ho.w = ((1.f - z) * nn + z * hv.w) * m;
  }
  *(float4*)&h[(size_t)node * 128 + j4] = ho;
  if (writeX) {
    ushort4 hi, lo;
    hi.x = f2bf(ho.x); lo.x = f2bf(ho.x - bf2f(hi.x));
    hi.y = f2bf(ho.y); lo.y = f2bf(ho.y - bf2f(hi.y));
    hi.z = f2bf(ho.z); lo.z = f2bf(ho.z - bf2f(hi.z));
    hi.w = f2bf(ho.w); lo.w = f2bf(ho.w - bf2f(hi.w));
    *(ushort4*)&X[(size_t)node * 256 + j4]       = hi;
    *(ushort4*)&X[(size_t)node * 256 + 128 + j4] = lo;
  }
}

// ---------------- readout stage 1: PT[c][node] = ([hT,h0] @ Wcat)[node][c] ----------------
__global__ __launch_bounds__(256) void k_readP(const float* __restrict__ h,
                                               const float* __restrict__ h0,
                                               const float* __restrict__ Wg,
                                               const float* __restrict__ Wo,
                                               float* __restrict__ PT) {
  __shared__ float Xt[64][65];
  __shared__ float Wt[64][25];
  const int tid = threadIdx.x;
  const int node0 = blockIdx.x * 64;
  const int row = tid >> 2;
  const int cg  = tid & 3;
  float acc[6] = {0.f, 0.f, 0.f, 0.f, 0.f, 0.f};
  const int sr = tid >> 2;
  const int sk = (tid & 3) * 16;
  #pragma unroll
  for (int kb = 0; kb < 4; ++kb) {
    const float* src = (kb < 2 ? h : h0) + (size_t)(node0 + sr) * 128 + (kb & 1) * 64 + sk;
    #pragma unroll
    for (int q = 0; q < 4; ++q)
      *(float4*)&Xt[sr][sk + q * 4] = *(const float4*)(src + q * 4);
    #pragma unroll
    for (int j = 0; j < 6; ++j) {
      int idx = tid * 6 + j;
      int rk = idx / 24;
      int c24 = idx - rk * 24;
      int gk = kb * 64 + rk;
      float wv;
      if (c24 < 12) wv = Wg[(size_t)gk * TGT_ + c24];
      else          wv = (gk < 128) ? Wo[(size_t)gk * TGT_ + (c24 - 12)] : 0.f;
      Wt[rk][c24] = wv;
    }
    __syncthreads();
    #pragma unroll 8
    for (int k = 0; k < 64; ++k) {
      float x = Xt[row][k];
      #pragma unroll
      for (int j = 0; j < 6; ++j)
        acc[j] += x * Wt[k][cg * 6 + j];
    }
    __syncthreads();
  }
  #pragma unroll
  for (int j = 0; j < 6; ++j)
    PT[(size_t)(cg * 6 + j) * NODES + node0 + row] = acc[j];
}

// ---------------- readout stage 2 ----------------
__global__ __launch_bounds__(256) void k_readR(const float* __restrict__ PT,
                                               const float* __restrict__ maskR,
                                               const float* __restrict__ bg,
                                               const float* __restrict__ bo,
                                               float* __restrict__ out) {
  __shared__ float red[256];
  const int tid = threadIdx.x;
  const int b = blockIdx.x / TGT_;
  const int t = blockIdx.x - b * TGT_;
  const float bgt = bg[t], bot = bo[t];
  float s = 0.f;
  #pragma unroll
  for (int i = 0; i < 4; ++i) {
    int node = b * N_ + i * 256 + tid;
    float p1 = PT[(size_t)t * NODES + node] + bgt;
    float p2 = PT[(size_t)(12 + t) * NODES + node] + bot;
    s += sigmoidf_(p1) * p2 * maskR[node];
  }
  red[tid] = s;
  __syncthreads();
  #pragma unroll
  for (int off = 128; off > 0; off >>= 1) {
    if (tid < off) red[tid] += red[tid + off];
    __syncthreads();
  }
  if (tid == 0) out[b * TGT_ + t] = red[0];
}

extern "C" void kernel_launch(void* const* d_in, const int* in_sizes, int n_in,
                              void* d_out, int out_size, void* d_ws, size_t ws_size,
                              hipStream_t stream) {
  (void)in_sizes; (void)n_in; (void)out_size; (void)ws_size;
  const float* g    = (const float*)d_in[0];
  const float* h_in = (const float*)d_in[1];
  const int*   e    = (const int*)d_in[2];
  const float* A    = (const float*)d_in[3];
  const float* Wi   = (const float*)d_in[4];
  const float* Wh   = (const float*)d_in[5];
  const float* bi   = (const float*)d_in[6];
  const float* bh   = (const float*)d_in[7];
  const float* Wg   = (const float*)d_in[8];
  const float* bg   = (const float*)d_in[9];
  const float* Wo   = (const float*)d_in[10];
  const float* bo   = (const float*)d_in[11];
  float* out = (float*)d_out;
  float* ws  = (float*)d_ws;

  // workspace layout (~92 MB):
  float* h     = ws;                                   // 1,048,576 f
  float* h0    = h + (size_t)NODES * H_;               // 1,048,576 f
  float* maskA = h0 + (size_t)NODES * H_;              // 8192 f
  float* maskR = maskA + NODES;                        // 8192 f
  float* PT    = maskR + NODES;                        // 196,608 f (readout scratch)
  unsigned short* X    = (unsigned short*)(PT + 24 * NODES);  // 2,097,152 us (h hi|lo)
  unsigned short* ATh  = X + (size_t)NODES * 256;      // 81,920 us
  unsigned short* ATl  = ATh + CAT_ * 128;             // 81,920 us
  unsigned short* WiTh = ATl + CAT_ * 128;             // 49,152 us
  unsigned short* WiTl = WiTh + 384 * 128;             // 49,152 us
  unsigned short* WhTh = WiTl + 384 * 128;             // 49,152 us
  unsigned short* WhTl = WhTh + 384 * 128;             // 49,152 us
  unsigned short* Gb   = WhTl + 384 * 128;             // 8,388,608 us (16.8 MB)
  unsigned char*  Eb   = (unsigned char*)(Gb + (size_t)NODES * N_);   // 8,388,608 u8
  float* aggP = (float*)(Eb + (size_t)NODES * N_);     // KSPLIT * 1,048,576 f (16.8 MB)
  unsigned short* McatT = (unsigned short*)(aggP + (size_t)KSPLIT * NODES * MSG2); // 10.5 MB
  float* gates = (float*)(McatT + (size_t)B_ * L_ * MSG2 * N_);       // 6,291,456 f (25.2 MB)

  k_prep<<<NODES / 4 + (CAT_ * 128) / 256 + (2 * 384 * 128) / 256, 256, 0, stream>>>(
      h_in, A, Wi, Wh, h, h0, X, maskA, maskR, ATh, ATl, WiTh, WiTl, WhTh, WhTl);
  k_pack<<<(NODES * N_ / 8) / 256, 256, 0, stream>>>(g, e, Gb, Eb);
  for (int layer = 0; layer < NLAYERS_; ++layer) {
    k_gemmT<<<dim3(CAT_ / 128, NODES / 64), 256, 0, stream>>>(X, ATh, ATl, McatT);
    k_agg_mfma<<<(N_ / 64) * 2 * KSPLIT * B_, 256, 0, stream>>>(Gb, Eb, McatT, aggP);
    k_gates_mfma<<<dim3(384 / 128, NODES / 64, 2), 256, 0, stream>>>(aggP, X, WiTh, WiTl, WhTh, WhTl, gates);
    k_gru_elt<<<NODES / 8, 256, 0, stream>>>(gates, bi, bh, maskA, h, X,
                                             (layer < NLAYERS_ - 1) ? 1 : 0);
  }
  k_readP<<<NODES / 64, 256, 0, stream>>>(h, h0, Wg, Wo, PT);
  k_readR<<<B_ * TGT_, 256, 0, stream>>>(PT, maskR, bg, bo, out);
}